// Round 1
// baseline (4773.019 us; speedup 1.0000x reference)
//
#include <hip/hip_runtime.h>
#include <math.h>

// ---------------- problem constants ----------------
#define BATCH 4
#define NTOK  2304      // (96/2)^2
#define DIM   256
#define NHEADS 8
#define DKH   32
#define HCDIM 48
#define KSEL  345       // int(0.15 * 2304)
#define NKT   36        // 2304 / 64
#define LN_EPS 1e-5f

// ---------------- patch embed + pos ----------------
// one block per (b, n); 256 threads = d
__global__ __launch_bounds__(256) void k_patch_embed(
    const float* __restrict__ x, const float* __restrict__ pw,
    const float* __restrict__ pb, const float* __restrict__ pos,
    float* __restrict__ tokens) {
  int blk = blockIdx.x;
  int b = blk / NTOK, n = blk % NTOK;
  int hc = n / HCDIM, wc = n % HCDIM;
  __shared__ float xs[12];
  int t = threadIdx.x;
  if (t < 12) {
    int c = t >> 2, p = (t >> 1) & 1, q = t & 1;
    xs[t] = x[((b * 3 + c) * 96 + (hc * 2 + p)) * 96 + (wc * 2 + q)];
  }
  __syncthreads();
  float acc = pb[t];
#pragma unroll
  for (int i = 0; i < 12; ++i) acc += xs[i] * pw[t * 12 + i];
  tokens[(size_t)(b * NTOK + n) * DIM + t] = acc + pos[n * DIM + t];
}

// ---------------- importance MLP -> scores ----------------
// 16 tokens per block; 256 threads = hidden unit j
__global__ __launch_bounds__(256) void k_importance(
    const float* __restrict__ tokens, const float* __restrict__ w1,
    const float* __restrict__ b1, const float* __restrict__ w2,
    const float* __restrict__ b2, float* __restrict__ scores) {
  __shared__ float ts[16 * 256];
  __shared__ float hw[16 * 256];
  int base = blockIdx.x * 16;  // token index over B*N
  int t = threadIdx.x;
  for (int i = t; i < 16 * 256; i += 256) ts[i] = tokens[(size_t)base * 256 + i];
  __syncthreads();
  float acc[16];
#pragma unroll
  for (int r = 0; r < 16; ++r) acc[r] = b1[t];
  for (int i = 0; i < 256; ++i) {
    float w = w1[i * 256 + t];
#pragma unroll
    for (int r = 0; r < 16; ++r) acc[r] += ts[r * 256 + i] * w;
  }
  float w2v = w2[t];
#pragma unroll
  for (int r = 0; r < 16; ++r) hw[r * 256 + t] = fmaxf(acc[r], 0.f) * w2v;
  __syncthreads();
  if (t < 16) {
    float s = b2[0];
    for (int i = 0; i < 256; ++i) s += hw[t * 256 + i];
    scores[base + t] = 1.f / (1.f + expf(-s));
  }
}

// ---------------- exact bottom-k selection (radix bit-select) ----------------
// one block per batch. mask[i]=1 -> key i dropped. ties -> lowest index first
// (matches lax.top_k on -scores). scores>0 so uint order == float order.
__global__ __launch_bounds__(256) void k_select(const float* __restrict__ scores,
                                                int* __restrict__ mask) {
  int b = blockIdx.x, t = threadIdx.x;
  __shared__ unsigned sb[NTOK];
  __shared__ int cnt;
  for (int i = t; i < NTOK; i += 256) sb[i] = __float_as_uint(scores[b * NTOK + i]);
  __syncthreads();
  unsigned prefix = 0;
  int r = KSEL;  // 1-indexed rank of the k-th smallest
  for (int bit = 31; bit >= 0; --bit) {
    if (t == 0) cnt = 0;
    __syncthreads();
    unsigned bmask = 1u << bit;
    unsigned hmask = (bit == 31) ? 0u : ~((bmask << 1) - 1u);
    int local = 0;
    for (int i = t; i < NTOK; i += 256)
      if ((sb[i] & hmask) == prefix && !(sb[i] & bmask)) local++;
    if (local) atomicAdd(&cnt, local);
    __syncthreads();
    int c0 = cnt;
    if (r > c0) { r -= c0; prefix |= bmask; }
    __syncthreads();
  }
  unsigned v = prefix;  // exact k-th smallest bit pattern
  if (t == 0) cnt = 0;
  __syncthreads();
  int local = 0;
  for (int i = t; i < NTOK; i += 256)
    if (sb[i] < v) local++;
  if (local) atomicAdd(&cnt, local);
  __syncthreads();
  int rem = KSEL - cnt;  // how many ties (== v) get masked, by index order
  for (int i = t; i < NTOK; i += 256)
    if (sb[i] != v) mask[b * NTOK + i] = (sb[i] < v) ? 1 : 0;
  if (t == 0) {
    int c = 0;
    for (int i = 0; i < NTOK; ++i)
      if (sb[i] == v) { mask[b * NTOK + i] = (c < rem) ? 1 : 0; c++; }
  }
}

// ---------------- LayerNorm (one block per token) ----------------
__global__ __launch_bounds__(256) void k_layernorm(
    const float* __restrict__ in, float* __restrict__ out,
    const float* __restrict__ g, const float* __restrict__ bta) {
  int row = blockIdx.x;
  int t = threadIdx.x;
  float v = in[(size_t)row * DIM + t];
  float s = v, ss = v * v;
#pragma unroll
  for (int o = 32; o > 0; o >>= 1) {
    s += __shfl_down(s, o);
    ss += __shfl_down(ss, o);
  }
  __shared__ float ps[4], pss[4], mb[2];
  int wid = t >> 6, lane = t & 63;
  if (lane == 0) { ps[wid] = s; pss[wid] = ss; }
  __syncthreads();
  if (t == 0) {
    float S = ps[0] + ps[1] + ps[2] + ps[3];
    float SS = pss[0] + pss[1] + pss[2] + pss[3];
    float m = S * (1.f / DIM);
    float var = SS * (1.f / DIM) - m * m;
    mb[0] = m;
    mb[1] = rsqrtf(var + LN_EPS);
  }
  __syncthreads();
  out[(size_t)row * DIM + t] = (v - mb[0]) * mb[1] * g[t] + bta[t];
}

// ---------------- tiled fp32 GEMM: out = res + act(A@W + bias) ----------------
// A: M x K (row-major), W: K x Nc (row-major). grid = (Nc/64, M/64), 256 thr.
// act: 0 = none, 1 = exact gelu. res may be null or alias out (same M x Nc).
__global__ __launch_bounds__(256) void k_gemm(
    const float* __restrict__ A, const float* __restrict__ W,
    const float* __restrict__ bias, const float* res, float* out,
    int K, int Nc, int act) {
  __shared__ float As[16][68];  // [k][m], stride 68 keeps float4 alignment
  __shared__ float Ws[16][64];  // [k][n]
  int m0 = blockIdx.y * 64;
  int n0 = blockIdx.x * 64;
  int t = threadIdx.x;
  int ty = t >> 4, tx = t & 15;
  int r0 = ty * 4, c0 = tx * 4;
  float acc[4][4] = {};
  for (int k0 = 0; k0 < K; k0 += 16) {
    for (int i = t; i < 64 * 16; i += 256) {
      int r = i >> 4, c = i & 15;
      As[c][r] = A[(size_t)(m0 + r) * K + k0 + c];
    }
    for (int i = t; i < 16 * 64; i += 256) {
      int r = i >> 6, c = i & 63;
      Ws[r][c] = W[(size_t)(k0 + r) * Nc + n0 + c];
    }
    __syncthreads();
#pragma unroll
    for (int kk = 0; kk < 16; ++kk) {
      float4 av = *reinterpret_cast<const float4*>(&As[kk][r0]);
      float4 bv = *reinterpret_cast<const float4*>(&Ws[kk][c0]);
      acc[0][0] += av.x * bv.x; acc[0][1] += av.x * bv.y;
      acc[0][2] += av.x * bv.z; acc[0][3] += av.x * bv.w;
      acc[1][0] += av.y * bv.x; acc[1][1] += av.y * bv.y;
      acc[1][2] += av.y * bv.z; acc[1][3] += av.y * bv.w;
      acc[2][0] += av.z * bv.x; acc[2][1] += av.z * bv.y;
      acc[2][2] += av.z * bv.z; acc[2][3] += av.z * bv.w;
      acc[3][0] += av.w * bv.x; acc[3][1] += av.w * bv.y;
      acc[3][2] += av.w * bv.z; acc[3][3] += av.w * bv.w;
    }
    __syncthreads();
  }
#pragma unroll
  for (int i = 0; i < 4; ++i) {
#pragma unroll
    for (int j = 0; j < 4; ++j) {
      size_t m = m0 + r0 + i;
      int c = n0 + c0 + j;
      float val = acc[i][j] + bias[c];
      if (act == 1) val = 0.5f * val * (1.f + erff(val * 0.70710678118654752f));
      if (res) val += res[m * Nc + c];
      out[m * Nc + c] = val;
    }
  }
}

// ---------------- flash attention with key mask ----------------
// grid = (36 q-tiles, 8 heads, 4 batch); 256 threads.
// qkv layout: [b, n, 768] with q|k|v at +0|+256|+512, head h at +h*32.
__global__ __launch_bounds__(256) void k_attn(
    const float* __restrict__ qkv, const int* __restrict__ mask,
    float* __restrict__ out) {
  int qt = blockIdx.x, h = blockIdx.y, b = blockIdx.z;
  int t = threadIdx.x;
  int ty = t >> 4, tx = t & 15;
  int r0 = ty * 4;   // query rows within tile
  int c0 = tx * 4;   // key cols within tile
  int n0 = qt * 64;
  __shared__ float Qs[32][68];  // [d][row], scaled
  __shared__ float Ks[32][68];  // [d][col]
  __shared__ float Vs[64][34];  // [col][d]
  __shared__ float Ps[64][68];  // [row][col]
  __shared__ int ms[64];
  const float scale = 0.17677669529663687f;  // 1/sqrt(32)

  const float* Qg = qkv + (size_t)(b * NTOK + n0) * 768 + h * 32;
  const float* Kg = qkv + (size_t)b * NTOK * 768 + 256 + h * 32;
  const float* Vg = Kg + 256;
  for (int i = t; i < 64 * 32; i += 256) {
    int r = i >> 5, d = i & 31;
    Qs[d][r] = Qg[(size_t)r * 768 + d] * scale;
  }
  float m_run[4], l_run[4], o_acc[4][2];
#pragma unroll
  for (int i = 0; i < 4; ++i) {
    m_run[i] = -INFINITY; l_run[i] = 0.f; o_acc[i][0] = 0.f; o_acc[i][1] = 0.f;
  }
  for (int kt = 0; kt < NKT; ++kt) {
    __syncthreads();  // previous tile fully consumed (also covers Q load)
    int kbase = kt * 64;
    for (int i = t; i < 64 * 32; i += 256) {
      int r = i >> 5, d = i & 31;
      Ks[d][r] = Kg[(size_t)(kbase + r) * 768 + d];
      Vs[r][d] = Vg[(size_t)(kbase + r) * 768 + d];
    }
    if (t < 64) ms[t] = mask[b * NTOK + kbase + t];
    __syncthreads();
    float s[4][4] = {};
#pragma unroll
    for (int d = 0; d < 32; ++d) {
      float4 qv = *reinterpret_cast<const float4*>(&Qs[d][r0]);
      float4 kv = *reinterpret_cast<const float4*>(&Ks[d][c0]);
      s[0][0] += qv.x * kv.x; s[0][1] += qv.x * kv.y; s[0][2] += qv.x * kv.z; s[0][3] += qv.x * kv.w;
      s[1][0] += qv.y * kv.x; s[1][1] += qv.y * kv.y; s[1][2] += qv.y * kv.z; s[1][3] += qv.y * kv.w;
      s[2][0] += qv.z * kv.x; s[2][1] += qv.z * kv.y; s[2][2] += qv.z * kv.z; s[2][3] += qv.z * kv.w;
      s[3][0] += qv.w * kv.x; s[3][1] += qv.w * kv.y; s[3][2] += qv.w * kv.z; s[3][3] += qv.w * kv.w;
    }
#pragma unroll
    for (int j = 0; j < 4; ++j) {
      if (ms[c0 + j]) {
        s[0][j] = -INFINITY; s[1][j] = -INFINITY;
        s[2][j] = -INFINITY; s[3][j] = -INFINITY;
      }
    }
#pragma unroll
    for (int i = 0; i < 4; ++i) {
      float mx = fmaxf(fmaxf(s[i][0], s[i][1]), fmaxf(s[i][2], s[i][3]));
#pragma unroll
      for (int o = 1; o < 16; o <<= 1) mx = fmaxf(mx, __shfl_xor(mx, o));
      float m_new = fmaxf(m_run[i], mx);
      float alpha;
      if (m_new == -INFINITY) {  // all keys so far masked: keep p=0, no rescale
        alpha = 1.f;
        s[i][0] = s[i][1] = s[i][2] = s[i][3] = 0.f;
      } else {
        alpha = expf(m_run[i] - m_new);  // m_run=-inf -> 0
        float psum = 0.f;
#pragma unroll
        for (int j = 0; j < 4; ++j) { s[i][j] = expf(s[i][j] - m_new); psum += s[i][j]; }
#pragma unroll
        for (int o = 1; o < 16; o <<= 1) psum += __shfl_xor(psum, o);
        l_run[i] = l_run[i] * alpha + psum;
      }
      m_run[i] = m_new;
      o_acc[i][0] *= alpha;
      o_acc[i][1] *= alpha;
      *reinterpret_cast<float4*>(&Ps[r0 + i][c0]) =
          make_float4(s[i][0], s[i][1], s[i][2], s[i][3]);
    }
    __syncthreads();
    int d0 = tx * 2;
#pragma unroll 2
    for (int j4 = 0; j4 < 64; j4 += 4) {
      float v00 = Vs[j4 + 0][d0], v01 = Vs[j4 + 0][d0 + 1];
      float v10 = Vs[j4 + 1][d0], v11 = Vs[j4 + 1][d0 + 1];
      float v20 = Vs[j4 + 2][d0], v21 = Vs[j4 + 2][d0 + 1];
      float v30 = Vs[j4 + 3][d0], v31 = Vs[j4 + 3][d0 + 1];
#pragma unroll
      for (int i = 0; i < 4; ++i) {
        float4 p = *reinterpret_cast<const float4*>(&Ps[r0 + i][j4]);
        o_acc[i][0] += p.x * v00 + p.y * v10 + p.z * v20 + p.w * v30;
        o_acc[i][1] += p.x * v01 + p.y * v11 + p.z * v21 + p.w * v31;
      }
    }
  }
  float* Og = out + (size_t)(b * NTOK + n0) * DIM + h * 32;
  int d0 = tx * 2;
#pragma unroll
  for (int i = 0; i < 4; ++i) {
    float inv = 1.f / l_run[i];  // always >0: at least one key unmasked overall
    Og[(size_t)(r0 + i) * DIM + d0] = o_acc[i][0] * inv;
    Og[(size_t)(r0 + i) * DIM + d0 + 1] = o_acc[i][1] * inv;
  }
}

// ---------------- final mean over tokens ----------------
__global__ __launch_bounds__(256) void k_mean_partial(const float* __restrict__ in,
                                                      float* __restrict__ part) {
  int blk = blockIdx.x;
  int b = blk / NKT, ch = blk % NKT;
  int d = threadIdx.x;
  const float* p = in + (size_t)(b * NTOK + ch * 64) * DIM + d;
  float s = 0.f;
  for (int n = 0; n < 64; ++n) s += p[(size_t)n * DIM];
  part[(size_t)blk * DIM + d] = s;
}

__global__ __launch_bounds__(256) void k_mean_final(const float* __restrict__ part,
                                                    float* __restrict__ out) {
  int b = blockIdx.x, d = threadIdx.x;
  float s = 0.f;
  for (int c = 0; c < NKT; ++c) s += part[(size_t)(b * NKT + c) * DIM + d];
  out[b * DIM + d] = s * (1.0f / NTOK);
}

// ---------------- driver ----------------
extern "C" void kernel_launch(void* const* d_in, const int* in_sizes, int n_in,
                              void* d_out, int out_size, void* d_ws, size_t ws_size,
                              hipStream_t stream) {
  (void)in_sizes; (void)n_in; (void)out_size;
  const float* x       = (const float*)d_in[0];
  const float* patch_w = (const float*)d_in[1];
  const float* patch_b = (const float*)d_in[2];
  const float* pos     = (const float*)d_in[3];
  const float* imp_w1  = (const float*)d_in[4];
  const float* imp_b1  = (const float*)d_in[5];
  const float* imp_w2  = (const float*)d_in[6];
  const float* imp_b2  = (const float*)d_in[7];
  const float* ln1_g   = (const float*)d_in[8];
  const float* ln1_b   = (const float*)d_in[9];
  const float* qkv_w   = (const float*)d_in[10];
  const float* qkv_b   = (const float*)d_in[11];
  const float* proj_w  = (const float*)d_in[12];
  const float* proj_b  = (const float*)d_in[13];
  const float* ln2_g   = (const float*)d_in[14];
  const float* ln2_b   = (const float*)d_in[15];
  const float* mlp_w1  = (const float*)d_in[16];
  const float* mlp_b1  = (const float*)d_in[17];
  const float* mlp_w2  = (const float*)d_in[18];
  const float* mlp_b2  = (const float*)d_in[19];
  const float* out_g   = (const float*)d_in[20];
  const float* out_b   = (const float*)d_in[21];
  float* out = (float*)d_out;

  const size_t TOK = (size_t)BATCH * NTOK * DIM;        // 2,359,296
  const size_t BIG = (size_t)BATCH * NTOK * 1024;       // 9,437,184
  float* ws      = (float*)d_ws;
  float* tokens  = ws;
  float* scratch = tokens + TOK;
  float* big     = scratch + TOK;                       // qkv (3D) / mlp hidden (4D) / mean partials
  float* scoresp = big + BIG;
  int*   maskp   = (int*)(scoresp + (size_t)BATCH * NTOK);
  size_t need = (2 * TOK + BIG + 2 * (size_t)BATCH * NTOK) * 4;
  if (ws_size < need) return;  // workspace too small: fail loudly via wrong output

  k_patch_embed<<<dim3(BATCH * NTOK), 256, 0, stream>>>(x, patch_w, patch_b, pos, tokens);
  k_importance<<<dim3(BATCH * NTOK / 16), 256, 0, stream>>>(tokens, imp_w1, imp_b1,
                                                            imp_w2, imp_b2, scoresp);
  k_select<<<dim3(BATCH), 256, 0, stream>>>(scoresp, maskp);

  const int M = BATCH * NTOK;  // 9216
  for (int l = 0; l < 3; ++l) {
    k_layernorm<<<dim3(M), 256, 0, stream>>>(tokens, scratch, ln1_g + l * DIM, ln1_b + l * DIM);
    k_gemm<<<dim3(768 / 64, M / 64), 256, 0, stream>>>(
        scratch, qkv_w + (size_t)l * DIM * 768, qkv_b + l * 768, nullptr, big, DIM, 768, 0);
    k_attn<<<dim3(NKT, NHEADS, BATCH), 256, 0, stream>>>(big, maskp, scratch);
    k_gemm<<<dim3(DIM / 64, M / 64), 256, 0, stream>>>(
        scratch, proj_w + (size_t)l * DIM * DIM, proj_b + l * DIM, tokens, tokens, DIM, DIM, 0);
    k_layernorm<<<dim3(M), 256, 0, stream>>>(tokens, scratch, ln2_g + l * DIM, ln2_b + l * DIM);
    k_gemm<<<dim3(1024 / 64, M / 64), 256, 0, stream>>>(
        scratch, mlp_w1 + (size_t)l * DIM * 1024, mlp_b1 + l * 1024, nullptr, big, DIM, 1024, 1);
    k_gemm<<<dim3(DIM / 64, M / 64), 256, 0, stream>>>(
        big, mlp_w2 + (size_t)l * 1024 * DIM, mlp_b2 + l * DIM, tokens, tokens, 1024, DIM, 0);
  }
  k_layernorm<<<dim3(M), 256, 0, stream>>>(tokens, scratch, out_g, out_b);
  k_mean_partial<<<dim3(BATCH * NKT), 256, 0, stream>>>(scratch, big);
  k_mean_final<<<dim3(BATCH), 256, 0, stream>>>(big, out);
}

// Round 2
// 1124.111 us; speedup vs baseline: 4.2460x; 4.2460x over previous
//
#include <hip/hip_runtime.h>
#include <math.h>

// ---------------- problem constants ----------------
#define BATCH 4
#define NTOK  2304      // (96/2)^2
#define DIM   256
#define NHEADS 8
#define HCDIM 48
#define KSEL  345       // int(0.15 * 2304)
#define NKT   36        // 2304 / 64
#define LN_EPS 1e-5f

typedef __attribute__((ext_vector_type(8))) short bf16x8;  // 8 bf16 (4 VGPRs)
typedef __attribute__((ext_vector_type(4))) float f32x4;   // MFMA accumulator

__device__ __forceinline__ unsigned short f2bf(float x) {
  union { float f; unsigned u; } v; v.f = x;
  return (unsigned short)((v.u + 0x7FFFu + ((v.u >> 16) & 1u)) >> 16);  // RNE
}

// ---------------- patch embed + pos (fp32) ----------------
__global__ __launch_bounds__(256) void k_patch_embed(
    const float* __restrict__ x, const float* __restrict__ pw,
    const float* __restrict__ pb, const float* __restrict__ pos,
    float* __restrict__ tokens) {
  int blk = blockIdx.x;
  int b = blk / NTOK, n = blk % NTOK;
  int hc = n / HCDIM, wc = n % HCDIM;
  __shared__ float xs[12];
  int t = threadIdx.x;
  if (t < 12) {
    int c = t >> 2, p = (t >> 1) & 1, q = t & 1;
    xs[t] = x[((b * 3 + c) * 96 + (hc * 2 + p)) * 96 + (wc * 2 + q)];
  }
  __syncthreads();
  float acc = pb[t];
#pragma unroll
  for (int i = 0; i < 12; ++i) acc += xs[i] * pw[t * 12 + i];
  tokens[(size_t)(b * NTOK + n) * DIM + t] = acc + pos[n * DIM + t];
}

// ---------------- importance MLP -> scores (fp32, exact) ----------------
__global__ __launch_bounds__(256) void k_importance(
    const float* __restrict__ tokens, const float* __restrict__ w1,
    const float* __restrict__ b1, const float* __restrict__ w2,
    const float* __restrict__ b2, float* __restrict__ scores) {
  __shared__ float ts[16 * 256];
  __shared__ float hw[16 * 256];
  int base = blockIdx.x * 16;
  int t = threadIdx.x;
  for (int i = t; i < 16 * 256; i += 256) ts[i] = tokens[(size_t)base * 256 + i];
  __syncthreads();
  float acc[16];
#pragma unroll
  for (int r = 0; r < 16; ++r) acc[r] = b1[t];
  for (int i = 0; i < 256; ++i) {
    float w = w1[i * 256 + t];
#pragma unroll
    for (int r = 0; r < 16; ++r) acc[r] += ts[r * 256 + i] * w;
  }
  float w2v = w2[t];
#pragma unroll
  for (int r = 0; r < 16; ++r) hw[r * 256 + t] = fmaxf(acc[r], 0.f) * w2v;
  __syncthreads();
  if (t < 16) {
    float s = b2[0];
    for (int i = 0; i < 256; ++i) s += hw[t * 256 + i];
    scores[base + t] = 1.f / (1.f + expf(-s));
  }
}

// ---------------- exact bottom-k -> additive float mask (0 / -inf) ----------------
__global__ __launch_bounds__(256) void k_select(const float* __restrict__ scores,
                                                float* __restrict__ maskf) {
  int b = blockIdx.x, t = threadIdx.x;
  __shared__ unsigned sb[NTOK];
  __shared__ int cnt;
  for (int i = t; i < NTOK; i += 256) sb[i] = __float_as_uint(scores[b * NTOK + i]);
  __syncthreads();
  unsigned prefix = 0;
  int r = KSEL;
  for (int bit = 31; bit >= 0; --bit) {
    if (t == 0) cnt = 0;
    __syncthreads();
    unsigned bmask = 1u << bit;
    unsigned hmask = (bit == 31) ? 0u : ~((bmask << 1) - 1u);
    int local = 0;
    for (int i = t; i < NTOK; i += 256)
      if ((sb[i] & hmask) == prefix && !(sb[i] & bmask)) local++;
    if (local) atomicAdd(&cnt, local);
    __syncthreads();
    int c0 = cnt;
    if (r > c0) { r -= c0; prefix |= bmask; }
    __syncthreads();
  }
  unsigned v = prefix;
  if (t == 0) cnt = 0;
  __syncthreads();
  int local = 0;
  for (int i = t; i < NTOK; i += 256)
    if (sb[i] < v) local++;
  if (local) atomicAdd(&cnt, local);
  __syncthreads();
  int rem = KSEL - cnt;
  for (int i = t; i < NTOK; i += 256)
    if (sb[i] != v) maskf[b * NTOK + i] = (sb[i] < v) ? -INFINITY : 0.0f;
  if (t == 0) {
    int c = 0;
    for (int i = 0; i < NTOK; ++i)
      if (sb[i] == v) { maskf[b * NTOK + i] = (c < rem) ? -INFINITY : 0.0f; c++; }
  }
}

// ---------------- LayerNorm -> bf16 out ----------------
__global__ __launch_bounds__(256) void k_ln_bf(
    const float* __restrict__ in, unsigned short* __restrict__ out,
    const float* __restrict__ g, const float* __restrict__ bta) {
  int row = blockIdx.x;
  int t = threadIdx.x;
  float v = in[(size_t)row * DIM + t];
  float s = v, ss = v * v;
#pragma unroll
  for (int o = 32; o > 0; o >>= 1) { s += __shfl_down(s, o); ss += __shfl_down(ss, o); }
  __shared__ float ps[4], pss[4], mb[2];
  int wid = t >> 6, lane = t & 63;
  if (lane == 0) { ps[wid] = s; pss[wid] = ss; }
  __syncthreads();
  if (t == 0) {
    float S = ps[0] + ps[1] + ps[2] + ps[3];
    float SS = pss[0] + pss[1] + pss[2] + pss[3];
    float m = S * (1.f / DIM);
    float var = SS * (1.f / DIM) - m * m;
    mb[0] = m; mb[1] = rsqrtf(var + LN_EPS);
  }
  __syncthreads();
  out[(size_t)row * DIM + t] = f2bf((v - mb[0]) * mb[1] * g[t] + bta[t]);
}

// ---------------- LayerNorm -> fp32 out (final) ----------------
__global__ __launch_bounds__(256) void k_ln_f32(
    const float* __restrict__ in, float* __restrict__ out,
    const float* __restrict__ g, const float* __restrict__ bta) {
  int row = blockIdx.x;
  int t = threadIdx.x;
  float v = in[(size_t)row * DIM + t];
  float s = v, ss = v * v;
#pragma unroll
  for (int o = 32; o > 0; o >>= 1) { s += __shfl_down(s, o); ss += __shfl_down(ss, o); }
  __shared__ float ps[4], pss[4], mb[2];
  int wid = t >> 6, lane = t & 63;
  if (lane == 0) { ps[wid] = s; pss[wid] = ss; }
  __syncthreads();
  if (t == 0) {
    float S = ps[0] + ps[1] + ps[2] + ps[3];
    float SS = pss[0] + pss[1] + pss[2] + pss[3];
    float m = S * (1.f / DIM);
    float var = SS * (1.f / DIM) - m * m;
    mb[0] = m; mb[1] = rsqrtf(var + LN_EPS);
  }
  __syncthreads();
  out[(size_t)row * DIM + t] = (v - mb[0]) * mb[1] * g[t] + bta[t];
}

// ---------------- weight convert + transpose: W[K][N] f32 -> WT[N][K] bf16 ----------------
__global__ __launch_bounds__(256) void k_wtrans(const float* __restrict__ W,
                                               unsigned short* __restrict__ WT,
                                               int K, int N) {
  __shared__ float tile[32][33];
  int nb = blockIdx.x * 32, kb = blockIdx.y * 32;
  const float* Wl = W + (size_t)blockIdx.z * K * N;
  unsigned short* WTl = WT + (size_t)blockIdx.z * K * N;
  int tx = threadIdx.x & 31, ty = threadIdx.x >> 5;  // 32x8
  for (int i = 0; i < 32; i += 8) tile[ty + i][tx] = Wl[(size_t)(kb + ty + i) * N + nb + tx];
  __syncthreads();
  for (int i = 0; i < 32; i += 8)
    WTl[(size_t)(nb + ty + i) * K + kb + tx] = f2bf(tile[tx][ty + i]);
}

// ---------------- bf16 MFMA GEMM: out = res + act(A @ BT^T + bias) ----------------
// A: [M][K] bf16, BT: [N][K] bf16. grid=(N/128, M/128), 256 thr (4 waves, 2x2).
__global__ __launch_bounds__(256) void k_gemm_bf16(
    const unsigned short* __restrict__ A, const unsigned short* __restrict__ BT,
    const float* __restrict__ bias, const float* __restrict__ res,
    float* __restrict__ outf, unsigned short* __restrict__ outb,
    int K, int N, int act) {
  __shared__ unsigned short As[128 * 40];  // stride 40 kills b128 bank conflicts
  __shared__ unsigned short Bs[128 * 40];
  int t = threadIdx.x;
  int m0 = blockIdx.y * 128, n0 = blockIdx.x * 128;
  int w = t >> 6, l = t & 63, lr = l & 15, qd = l >> 4;
  int wm = (w >> 1) * 64, wn = (w & 1) * 64;
  f32x4 acc[4][4];
#pragma unroll
  for (int i = 0; i < 4; ++i)
#pragma unroll
    for (int j = 0; j < 4; ++j)
#pragma unroll
      for (int r = 0; r < 4; ++r) acc[i][j][r] = 0.f;
  for (int k0 = 0; k0 < K; k0 += 32) {
    for (int i = t; i < 512; i += 256) {
      int row = i >> 2, ch = i & 3;
      *(float4*)(As + row * 40 + ch * 8) =
          *(const float4*)(A + (size_t)(m0 + row) * K + k0 + ch * 8);
      *(float4*)(Bs + row * 40 + ch * 8) =
          *(const float4*)(BT + (size_t)(n0 + row) * K + k0 + ch * 8);
    }
    __syncthreads();
    bf16x8 af[4], bfr[4];
#pragma unroll
    for (int mt = 0; mt < 4; ++mt)
      af[mt] = *(const bf16x8*)(As + (wm + mt * 16 + lr) * 40 + qd * 8);
#pragma unroll
    for (int nt = 0; nt < 4; ++nt)
      bfr[nt] = *(const bf16x8*)(Bs + (wn + nt * 16 + lr) * 40 + qd * 8);
#pragma unroll
    for (int mt = 0; mt < 4; ++mt)
#pragma unroll
      for (int nt = 0; nt < 4; ++nt)
        acc[mt][nt] = __builtin_amdgcn_mfma_f32_16x16x32_bf16(af[mt], bfr[nt],
                                                              acc[mt][nt], 0, 0, 0);
    __syncthreads();
  }
#pragma unroll
  for (int mt = 0; mt < 4; ++mt) {
#pragma unroll
    for (int nt = 0; nt < 4; ++nt) {
#pragma unroll
      for (int r = 0; r < 4; ++r) {
        size_t m = (size_t)m0 + wm + mt * 16 + qd * 4 + r;  // C/D: row=quad*4+reg
        int c = n0 + wn + nt * 16 + lr;                      //      col=lane&15
        float val = acc[mt][nt][r] + bias[c];
        if (act) val = 0.5f * val * (1.f + erff(val * 0.70710678118654752f));
        if (res) val += res[m * N + c];
        if (outf) outf[m * N + c] = val;
        if (outb) outb[m * N + c] = f2bf(val);
      }
    }
  }
}

// ---------------- flash attention, bf16 MFMA ----------------
// grid=(36,8,4), 256 thr; wave w owns q rows [qt*64+w*16, +16).
// qkv: [B*N][768] bf16 (q|k|v at +0/+256/+512, head h at +h*32).
__global__ __launch_bounds__(256) void k_attn_mfma(
    const unsigned short* __restrict__ qkv, const float* __restrict__ maskf,
    unsigned short* __restrict__ outb) {
  int qt = blockIdx.x, h = blockIdx.y, b = blockIdx.z;
  int t = threadIdx.x, w = t >> 6, l = t & 63, lr = l & 15, qd = l >> 4;
  __shared__ unsigned short Vt[32][72];      // [d][key], padded
  __shared__ unsigned short Pl[4][16][72];   // per-wave P [row][key], padded
  __shared__ float ms[64];
  const unsigned short* base = qkv + (size_t)b * NTOK * 768;
  int q0 = qt * 64 + w * 16;
  // Q fragment straight from global: A[m=lane&15][k=quad*8+j]
  bf16x8 qf = *(const bf16x8*)(base + (size_t)(q0 + lr) * 768 + h * 32 + qd * 8);
  const float scale = 0.17677669529663687f;  // 1/sqrt(32)
  float m_run[4], l_run[4];
  f32x4 oa[2];
#pragma unroll
  for (int r = 0; r < 4; ++r) {
    m_run[r] = -INFINITY; l_run[r] = 0.f; oa[0][r] = 0.f; oa[1][r] = 0.f;
  }
  for (int kt = 0; kt < NKT; ++kt) {
    int kb = kt * 64;
    __syncthreads();  // previous tile fully consumed
    {  // stage V transposed: wave w handles d rows [w*8, w*8+8), all 64 keys
      int key = l, d0 = w * 8;
      bf16x8 vv = *(const bf16x8*)(base + (size_t)(kb + key) * 768 + 512 + h * 32 + d0);
#pragma unroll
      for (int j = 0; j < 8; ++j) Vt[d0 + j][key] = (unsigned short)vv[j];
      if (t < 64) ms[t] = maskf[b * NTOK + kb + t];
    }
    __syncthreads();
    // S = Q K^T: B[k=d][n=key] read straight from global
    f32x4 s[4];
#pragma unroll
    for (int nt = 0; nt < 4; ++nt) {
      bf16x8 kf = *(const bf16x8*)(base + (size_t)(kb + nt * 16 + lr) * 768 + 256 +
                                   h * 32 + qd * 8);
      f32x4 z;
      z[0] = 0.f; z[1] = 0.f; z[2] = 0.f; z[3] = 0.f;
      s[nt] = __builtin_amdgcn_mfma_f32_16x16x32_bf16(qf, kf, z, 0, 0, 0);
    }
    float sv[4][4];
#pragma unroll
    for (int nt = 0; nt < 4; ++nt) {
      float cm = ms[nt * 16 + lr];
#pragma unroll
      for (int r = 0; r < 4; ++r) sv[nt][r] = s[nt][r] * scale + cm;
    }
    // online softmax per row (row = qd*4+r, uniform across the 16 lanes of a quad)
#pragma unroll
    for (int r = 0; r < 4; ++r) {
      float mt4 = fmaxf(fmaxf(sv[0][r], sv[1][r]), fmaxf(sv[2][r], sv[3][r]));
#pragma unroll
      for (int o = 1; o < 16; o <<= 1) mt4 = fmaxf(mt4, __shfl_xor(mt4, o));
      float m_new = fmaxf(m_run[r], mt4);
      float alpha, p0, p1, p2, p3;
      if (m_new == -INFINITY) {  // everything so far masked: keep zeros
        alpha = 1.f; p0 = p1 = p2 = p3 = 0.f;
      } else {
        alpha = __expf(m_run[r] - m_new);  // -inf -> 0
        p0 = __expf(sv[0][r] - m_new); p1 = __expf(sv[1][r] - m_new);
        p2 = __expf(sv[2][r] - m_new); p3 = __expf(sv[3][r] - m_new);
        float psum = p0 + p1 + p2 + p3;
#pragma unroll
        for (int o = 1; o < 16; o <<= 1) psum += __shfl_xor(psum, o);
        l_run[r] = l_run[r] * alpha + psum;
      }
      m_run[r] = m_new;
      oa[0][r] *= alpha; oa[1][r] *= alpha;
      int row = qd * 4 + r;
      Pl[w][row][0 * 16 + lr] = f2bf(p0);
      Pl[w][row][1 * 16 + lr] = f2bf(p1);
      Pl[w][row][2 * 16 + lr] = f2bf(p2);
      Pl[w][row][3 * 16 + lr] = f2bf(p3);
    }
    // O += P V : A[m=q][k=key] from Pl, B[k=key][n=d] from Vt (within-wave, no barrier)
#pragma unroll
    for (int half = 0; half < 2; ++half) {
      bf16x8 pf = *(const bf16x8*)(&Pl[w][lr][half * 32 + qd * 8]);
#pragma unroll
      for (int dt = 0; dt < 2; ++dt) {
        bf16x8 vf = *(const bf16x8*)(&Vt[dt * 16 + lr][half * 32 + qd * 8]);
        oa[dt] = __builtin_amdgcn_mfma_f32_16x16x32_bf16(pf, vf, oa[dt], 0, 0, 0);
      }
    }
  }
#pragma unroll
  for (int r = 0; r < 4; ++r) {
    float inv = 1.f / l_run[r];
    size_t row = (size_t)b * NTOK + q0 + qd * 4 + r;
    outb[row * 256 + h * 32 + lr] = f2bf(oa[0][r] * inv);
    outb[row * 256 + h * 32 + 16 + lr] = f2bf(oa[1][r] * inv);
  }
}

// ---------------- final mean over tokens ----------------
__global__ __launch_bounds__(256) void k_mean_partial(const float* __restrict__ in,
                                                      float* __restrict__ part) {
  int blk = blockIdx.x;
  int b = blk / NKT, ch = blk % NKT;
  int d = threadIdx.x;
  const float* p = in + (size_t)(b * NTOK + ch * 64) * DIM + d;
  float s = 0.f;
  for (int n = 0; n < 64; ++n) s += p[(size_t)n * DIM];
  part[(size_t)blk * DIM + d] = s;
}

__global__ __launch_bounds__(256) void k_mean_final(const float* __restrict__ part,
                                                    float* __restrict__ out) {
  int b = blockIdx.x, d = threadIdx.x;
  float s = 0.f;
  for (int c = 0; c < NKT; ++c) s += part[(size_t)(b * NKT + c) * DIM + d];
  out[b * DIM + d] = s * (1.0f / NTOK);
}

// ---------------- driver ----------------
extern "C" void kernel_launch(void* const* d_in, const int* in_sizes, int n_in,
                              void* d_out, int out_size, void* d_ws, size_t ws_size,
                              hipStream_t stream) {
  (void)in_sizes; (void)n_in; (void)out_size;
  const float* x       = (const float*)d_in[0];
  const float* patch_w = (const float*)d_in[1];
  const float* patch_b = (const float*)d_in[2];
  const float* pos     = (const float*)d_in[3];
  const float* imp_w1  = (const float*)d_in[4];
  const float* imp_b1  = (const float*)d_in[5];
  const float* imp_w2  = (const float*)d_in[6];
  const float* imp_b2  = (const float*)d_in[7];
  const float* ln1_g   = (const float*)d_in[8];
  const float* ln1_b   = (const float*)d_in[9];
  const float* qkv_w   = (const float*)d_in[10];
  const float* qkv_b   = (const float*)d_in[11];
  const float* proj_w  = (const float*)d_in[12];
  const float* proj_b  = (const float*)d_in[13];
  const float* ln2_g   = (const float*)d_in[14];
  const float* ln2_b   = (const float*)d_in[15];
  const float* mlp_w1  = (const float*)d_in[16];
  const float* mlp_b1  = (const float*)d_in[17];
  const float* mlp_w2  = (const float*)d_in[18];
  const float* mlp_b2  = (const float*)d_in[19];
  const float* out_g   = (const float*)d_in[20];
  const float* out_b   = (const float*)d_in[21];
  float* out = (float*)d_out;

  const int M = BATCH * NTOK;                 // 9216
  const size_t TOK = (size_t)M * DIM;         // 2,359,296

  char* p = (char*)d_ws;
  float* tokens = (float*)p;              p += TOK * 4;
  float* scoresp = (float*)p;             p += (size_t)M * 4;
  float* maskf = (float*)p;               p += (size_t)M * 4;
  unsigned short* act_bf = (unsigned short*)p;  p += TOK * 2;           // LN out / attn out
  unsigned short* big_bf = (unsigned short*)p;  p += (size_t)M * 1024 * 2;  // qkv / mlp hidden
  unsigned short* wq_t = (unsigned short*)p;    p += (size_t)3 * 768 * 256 * 2;
  unsigned short* wp_t = (unsigned short*)p;    p += (size_t)3 * 256 * 256 * 2;
  unsigned short* w1_t = (unsigned short*)p;    p += (size_t)3 * 1024 * 256 * 2;
  unsigned short* w2_t = (unsigned short*)p;    p += (size_t)3 * 256 * 1024 * 2;
  float* fscr = (float*)big_bf;     // final-LN fp32 scratch (big_bf dead by then)
  float* partials = (float*)act_bf; // mean partials (act_bf dead by then)
  if (ws_size < (size_t)(p - (char*)d_ws)) return;

  // weight convert+transpose (bf16, [N][K])
  k_wtrans<<<dim3(768 / 32, 256 / 32, 3), 256, 0, stream>>>(qkv_w, wq_t, 256, 768);
  k_wtrans<<<dim3(256 / 32, 256 / 32, 3), 256, 0, stream>>>(proj_w, wp_t, 256, 256);
  k_wtrans<<<dim3(1024 / 32, 256 / 32, 3), 256, 0, stream>>>(mlp_w1, w1_t, 256, 1024);
  k_wtrans<<<dim3(256 / 32, 1024 / 32, 3), 256, 0, stream>>>(mlp_w2, w2_t, 1024, 256);

  k_patch_embed<<<dim3(M), 256, 0, stream>>>(x, patch_w, patch_b, pos, tokens);
  k_importance<<<dim3(M / 16), 256, 0, stream>>>(tokens, imp_w1, imp_b1, imp_w2, imp_b2, scoresp);
  k_select<<<dim3(BATCH), 256, 0, stream>>>(scoresp, maskf);

  for (int l = 0; l < 3; ++l) {
    k_ln_bf<<<dim3(M), 256, 0, stream>>>(tokens, act_bf, ln1_g + l * DIM, ln1_b + l * DIM);
    k_gemm_bf16<<<dim3(6, 72), 256, 0, stream>>>(
        act_bf, wq_t + (size_t)l * 768 * 256, qkv_b + l * 768,
        nullptr, nullptr, big_bf, 256, 768, 0);
    k_attn_mfma<<<dim3(NKT, NHEADS, BATCH), 256, 0, stream>>>(big_bf, maskf, act_bf);
    k_gemm_bf16<<<dim3(2, 72), 256, 0, stream>>>(
        act_bf, wp_t + (size_t)l * 256 * 256, proj_b + l * DIM,
        tokens, tokens, nullptr, 256, 256, 0);
    k_ln_bf<<<dim3(M), 256, 0, stream>>>(tokens, act_bf, ln2_g + l * DIM, ln2_b + l * DIM);
    k_gemm_bf16<<<dim3(8, 72), 256, 0, stream>>>(
        act_bf, w1_t + (size_t)l * 1024 * 256, mlp_b1 + l * 1024,
        nullptr, nullptr, big_bf, 256, 1024, 1);
    k_gemm_bf16<<<dim3(2, 72), 256, 0, stream>>>(
        big_bf, w2_t + (size_t)l * 256 * 1024, mlp_b2 + l * DIM,
        tokens, tokens, nullptr, 1024, 256, 0);
  }
  k_ln_f32<<<dim3(M), 256, 0, stream>>>(tokens, fscr, out_g, out_b);
  k_mean_partial<<<dim3(BATCH * NKT), 256, 0, stream>>>(fscr, partials);
  k_mean_final<<<dim3(BATCH), 256, 0, stream>>>(partials, out);
}

// Round 3
// 779.314 us; speedup vs baseline: 6.1246x; 1.4424x over previous
//
#include <hip/hip_runtime.h>
#include <hip/hip_bf16.h>
#include <math.h>

// ---------------- problem constants ----------------
#define BATCH 4
#define NTOK  2304      // (96/2)^2
#define DIM   256
#define NHEADS 8
#define HCDIM 48
#define KSEL  345       // int(0.15 * 2304)
#define NKEEP 1959      // 2304 - 345
#define NKC   1984      // padded to 31*64
#define KT    31        // key tiles of 64
#define KREM  39        // real keys in last tile (1959 - 30*64)
#define LN_EPS 1e-5f

typedef __attribute__((ext_vector_type(8))) short bf16x8;  // 8 bf16 (4 VGPRs)
typedef __attribute__((ext_vector_type(4))) float f32x4;   // MFMA accumulator

__device__ __forceinline__ unsigned short f2bf(float x) {
  union { float f; unsigned u; } v; v.f = x;
  return (unsigned short)((v.u + 0x7FFFu + ((v.u >> 16) & 1u)) >> 16);  // RNE
}

// ---------------- patch embed + pos (fp32) ----------------
__global__ __launch_bounds__(256) void k_patch_embed(
    const float* __restrict__ x, const float* __restrict__ pw,
    const float* __restrict__ pb, const float* __restrict__ pos,
    float* __restrict__ tokens) {
  int blk = blockIdx.x;
  int b = blk / NTOK, n = blk % NTOK;
  int hc = n / HCDIM, wc = n % HCDIM;
  __shared__ float xs[12];
  int t = threadIdx.x;
  if (t < 12) {
    int c = t >> 2, p = (t >> 1) & 1, q = t & 1;
    xs[t] = x[((b * 3 + c) * 96 + (hc * 2 + p)) * 96 + (wc * 2 + q)];
  }
  __syncthreads();
  float acc = pb[t];
#pragma unroll
  for (int i = 0; i < 12; ++i) acc += xs[i] * pw[t * 12 + i];
  tokens[(size_t)(b * NTOK + n) * DIM + t] = acc + pos[n * DIM + t];
}

// ---------------- importance MLP -> scores (fp32, exact) ----------------
__global__ __launch_bounds__(256) void k_importance(
    const float* __restrict__ tokens, const float* __restrict__ w1,
    const float* __restrict__ b1, const float* __restrict__ w2,
    const float* __restrict__ b2, float* __restrict__ scores) {
  __shared__ float ts[16 * 256];
  __shared__ float hw[16 * 256];
  int base = blockIdx.x * 16;
  int t = threadIdx.x;
  for (int i = t; i < 16 * 256; i += 256) ts[i] = tokens[(size_t)base * 256 + i];
  __syncthreads();
  float acc[16];
#pragma unroll
  for (int r = 0; r < 16; ++r) acc[r] = b1[t];
  for (int i = 0; i < 256; ++i) {
    float w = w1[i * 256 + t];
#pragma unroll
    for (int r = 0; r < 16; ++r) acc[r] += ts[r * 256 + i] * w;
  }
  float w2v = w2[t];
#pragma unroll
  for (int r = 0; r < 16; ++r) hw[r * 256 + t] = fmaxf(acc[r], 0.f) * w2v;
  __syncthreads();
  if (t < 16) {
    float s = b2[0];
    for (int i = 0; i < 256; ++i) s += hw[t * 256 + i];
    scores[base + t] = 1.f / (1.f + expf(-s));
  }
}

// ------- exact bottom-k -> compaction map, + zero KV pad rows -------
// cmap[b*NTOK+n] = compact key index (0..1958) if kept, -1 if dropped.
// Ties broken by lowest index first (matches lax.top_k on -scores).
__global__ __launch_bounds__(256) void k_select(const float* __restrict__ scores,
                                                int* __restrict__ cmap,
                                                unsigned short* __restrict__ kvc) {
  int b = blockIdx.x, t = threadIdx.x;
  __shared__ unsigned sb[NTOK];
  __shared__ int cnt;
  __shared__ int pfl[256], pfe[256];
  __shared__ int remS;
  for (int i = t; i < NTOK; i += 256) sb[i] = __float_as_uint(scores[b * NTOK + i]);
  __syncthreads();
  unsigned prefix = 0;
  int r = KSEL;
  for (int bit = 31; bit >= 0; --bit) {
    if (t == 0) cnt = 0;
    __syncthreads();
    unsigned bmask = 1u << bit;
    unsigned hmask = (bit == 31) ? 0u : ~((bmask << 1) - 1u);
    int local = 0;
    for (int i = t; i < NTOK; i += 256)
      if ((sb[i] & hmask) == prefix && !(sb[i] & bmask)) local++;
    if (local) atomicAdd(&cnt, local);
    __syncthreads();
    int c0 = cnt;
    if (r > c0) { r -= c0; prefix |= bmask; }
    __syncthreads();
  }
  unsigned v = prefix;  // exact k-th smallest bit pattern
  // parallel prefix over contiguous chunks of 9 (2304 = 256*9)
  int cl = 0, ce = 0;
  int j0 = t * 9;
  for (int j = j0; j < j0 + 9; ++j) { cl += (sb[j] < v); ce += (sb[j] == v); }
  pfl[t] = cl; pfe[t] = ce;
  __syncthreads();
  if (t == 0) {
    int pl = 0, pe = 0;
    for (int i = 0; i < 256; ++i) {
      int a = pfl[i], e = pfe[i];
      pfl[i] = pl; pfe[i] = pe;
      pl += a; pe += e;
    }
    remS = KSEL - pl;  // how many ties get dropped (by index order)
  }
  __syncthreads();
  int pl = pfl[t], pe = pfe[t], rem = remS;
  for (int j = j0; j < j0 + 9; ++j) {
    bool less = sb[j] < v, eq = sb[j] == v;
    bool drop = less || (eq && pe < rem);
    int dropped_before = pl + (pe < rem ? pe : rem);
    cmap[b * NTOK + j] = drop ? -1 : (j - dropped_before);
    pl += less; pe += eq;
  }
  // zero KV pad rows (keys NKEEP..NKC-1), 512 bf16 per row
  for (int i = t; i < (NKC - NKEEP) * 512; i += 256)
    kvc[((size_t)b * NKC + NKEEP) * 512 + i] = 0;
}

// ---------------- LayerNorm -> bf16 out ----------------
__global__ __launch_bounds__(256) void k_ln_bf(
    const float* __restrict__ in, unsigned short* __restrict__ out,
    const float* __restrict__ g, const float* __restrict__ bta) {
  int row = blockIdx.x;
  int t = threadIdx.x;
  float v = in[(size_t)row * DIM + t];
  float s = v, ss = v * v;
#pragma unroll
  for (int o = 32; o > 0; o >>= 1) { s += __shfl_down(s, o); ss += __shfl_down(ss, o); }
  __shared__ float ps[4], pss[4], mb[2];
  int wid = t >> 6, lane = t & 63;
  if (lane == 0) { ps[wid] = s; pss[wid] = ss; }
  __syncthreads();
  if (t == 0) {
    float S = ps[0] + ps[1] + ps[2] + ps[3];
    float SS = pss[0] + pss[1] + pss[2] + pss[3];
    float m = S * (1.f / DIM);
    float var = SS * (1.f / DIM) - m * m;
    mb[0] = m; mb[1] = rsqrtf(var + LN_EPS);
  }
  __syncthreads();
  out[(size_t)row * DIM + t] = f2bf((v - mb[0]) * mb[1] * g[t] + bta[t]);
}

// ---------------- LayerNorm -> fp32 out (final) ----------------
__global__ __launch_bounds__(256) void k_ln_f32(
    const float* __restrict__ in, float* __restrict__ out,
    const float* __restrict__ g, const float* __restrict__ bta) {
  int row = blockIdx.x;
  int t = threadIdx.x;
  float v = in[(size_t)row * DIM + t];
  float s = v, ss = v * v;
#pragma unroll
  for (int o = 32; o > 0; o >>= 1) { s += __shfl_down(s, o); ss += __shfl_down(ss, o); }
  __shared__ float ps[4], pss[4], mb[2];
  int wid = t >> 6, lane = t & 63;
  if (lane == 0) { ps[wid] = s; pss[wid] = ss; }
  __syncthreads();
  if (t == 0) {
    float S = ps[0] + ps[1] + ps[2] + ps[3];
    float SS = pss[0] + pss[1] + pss[2] + pss[3];
    float m = S * (1.f / DIM);
    float var = SS * (1.f / DIM) - m * m;
    mb[0] = m; mb[1] = rsqrtf(var + LN_EPS);
  }
  __syncthreads();
  out[(size_t)row * DIM + t] = (v - mb[0]) * mb[1] * g[t] + bta[t];
}

// ---------------- weight convert + transpose: W[K][N] f32 -> WT[N][K] bf16 ----------------
__global__ __launch_bounds__(256) void k_wtrans(const float* __restrict__ W,
                                               unsigned short* __restrict__ WT,
                                               int K, int N) {
  __shared__ float tile[32][33];
  int nb = blockIdx.x * 32, kb = blockIdx.y * 32;
  const float* Wl = W + (size_t)blockIdx.z * K * N;
  unsigned short* WTl = WT + (size_t)blockIdx.z * K * N;
  int tx = threadIdx.x & 31, ty = threadIdx.x >> 5;  // 32x8
  for (int i = 0; i < 32; i += 8) tile[ty + i][tx] = Wl[(size_t)(kb + ty + i) * N + nb + tx];
  __syncthreads();
  for (int i = 0; i < 32; i += 8)
    WTl[(size_t)(nb + ty + i) * K + kb + tx] = f2bf(tile[tx][ty + i]);
}

// ---------------- bf16 MFMA GEMM 128x128: outb = act(A @ BT^T + bias) ----------------
__global__ __launch_bounds__(256) void k_gemm_bf16(
    const unsigned short* __restrict__ A, const unsigned short* __restrict__ BT,
    const float* __restrict__ bias, unsigned short* __restrict__ outb,
    int K, int N, int act) {
  __shared__ unsigned short As[128 * 40];
  __shared__ unsigned short Bs[128 * 40];
  int t = threadIdx.x;
  int m0 = blockIdx.y * 128, n0 = blockIdx.x * 128;
  int w = t >> 6, l = t & 63, lr = l & 15, qd = l >> 4;
  int wm = (w >> 1) * 64, wn = (w & 1) * 64;
  f32x4 acc[4][4];
#pragma unroll
  for (int i = 0; i < 4; ++i)
#pragma unroll
    for (int j = 0; j < 4; ++j)
#pragma unroll
      for (int r = 0; r < 4; ++r) acc[i][j][r] = 0.f;
  for (int k0 = 0; k0 < K; k0 += 32) {
    for (int i = t; i < 512; i += 256) {
      int row = i >> 2, ch = i & 3;
      *(float4*)(As + row * 40 + ch * 8) =
          *(const float4*)(A + (size_t)(m0 + row) * K + k0 + ch * 8);
      *(float4*)(Bs + row * 40 + ch * 8) =
          *(const float4*)(BT + (size_t)(n0 + row) * K + k0 + ch * 8);
    }
    __syncthreads();
    bf16x8 af[4], bfr[4];
#pragma unroll
    for (int mt = 0; mt < 4; ++mt)
      af[mt] = *(const bf16x8*)(As + (wm + mt * 16 + lr) * 40 + qd * 8);
#pragma unroll
    for (int nt = 0; nt < 4; ++nt)
      bfr[nt] = *(const bf16x8*)(Bs + (wn + nt * 16 + lr) * 40 + qd * 8);
#pragma unroll
    for (int mt = 0; mt < 4; ++mt)
#pragma unroll
      for (int nt = 0; nt < 4; ++nt)
        acc[mt][nt] = __builtin_amdgcn_mfma_f32_16x16x32_bf16(af[mt], bfr[nt],
                                                              acc[mt][nt], 0, 0, 0);
    __syncthreads();
  }
#pragma unroll
  for (int mt = 0; mt < 4; ++mt) {
#pragma unroll
    for (int nt = 0; nt < 4; ++nt) {
#pragma unroll
      for (int r = 0; r < 4; ++r) {
        size_t m = (size_t)m0 + wm + mt * 16 + qd * 4 + r;
        int c = n0 + wn + nt * 16 + lr;
        float val = acc[mt][nt][r] + bias[c];
        if (act) val = 0.5f * val * (1.f + erff(val * 0.70710678118654752f));
        outb[m * N + c] = f2bf(val);
      }
    }
  }
}

// ------------ QKV GEMM 128x128, N=768: split epilogue -------------
// cols 0..255 -> Qb (pre-scaled by 1/sqrt(32)); cols 256..767 -> KVc
// compacted by cmap (dropped keys not written; pad rows pre-zeroed).
__global__ __launch_bounds__(256) void k_gemm_qkv(
    const unsigned short* __restrict__ A, const unsigned short* __restrict__ BT,
    const float* __restrict__ bias, const int* __restrict__ cmap,
    unsigned short* __restrict__ Qb, unsigned short* __restrict__ KVc) {
  const int K = 256, N = 768;
  __shared__ unsigned short As[128 * 40];
  __shared__ unsigned short Bs[128 * 40];
  int t = threadIdx.x;
  int m0 = blockIdx.y * 128, n0 = blockIdx.x * 128;
  int w = t >> 6, l = t & 63, lr = l & 15, qd = l >> 4;
  int wm = (w >> 1) * 64, wn = (w & 1) * 64;
  f32x4 acc[4][4];
#pragma unroll
  for (int i = 0; i < 4; ++i)
#pragma unroll
    for (int j = 0; j < 4; ++j)
#pragma unroll
      for (int r = 0; r < 4; ++r) acc[i][j][r] = 0.f;
  for (int k0 = 0; k0 < K; k0 += 32) {
    for (int i = t; i < 512; i += 256) {
      int row = i >> 2, ch = i & 3;
      *(float4*)(As + row * 40 + ch * 8) =
          *(const float4*)(A + (size_t)(m0 + row) * K + k0 + ch * 8);
      *(float4*)(Bs + row * 40 + ch * 8) =
          *(const float4*)(BT + (size_t)(n0 + row) * K + k0 + ch * 8);
    }
    __syncthreads();
    bf16x8 af[4], bfr[4];
#pragma unroll
    for (int mt = 0; mt < 4; ++mt)
      af[mt] = *(const bf16x8*)(As + (wm + mt * 16 + lr) * 40 + qd * 8);
#pragma unroll
    for (int nt = 0; nt < 4; ++nt)
      bfr[nt] = *(const bf16x8*)(Bs + (wn + nt * 16 + lr) * 40 + qd * 8);
#pragma unroll
    for (int mt = 0; mt < 4; ++mt)
#pragma unroll
      for (int nt = 0; nt < 4; ++nt)
        acc[mt][nt] = __builtin_amdgcn_mfma_f32_16x16x32_bf16(af[mt], bfr[nt],
                                                              acc[mt][nt], 0, 0, 0);
    __syncthreads();
  }
  bool isQ = (n0 + wn) < 256;  // wave-uniform (64-col wave span never crosses 256)
#pragma unroll
  for (int mt = 0; mt < 4; ++mt) {
#pragma unroll
    for (int r = 0; r < 4; ++r) {
      int m = m0 + wm + mt * 16 + qd * 4 + r;
      int cpos = isQ ? 0 : cmap[m];
      int b = m / NTOK;
#pragma unroll
      for (int nt = 0; nt < 4; ++nt) {
        int c = n0 + wn + nt * 16 + lr;
        float val = acc[mt][nt][r] + bias[c];
        if (isQ) {
          Qb[(size_t)m * 256 + c] = f2bf(val * 0.17677669529663687f);
        } else if (cpos >= 0) {
          KVc[((size_t)b * NKC + cpos) * 512 + (c - 256)] = f2bf(val);
        }
      }
    }
  }
}

// ------------- bf16 MFMA GEMM 128x64: outf = res + A @ BT^T + bias -------------
__global__ __launch_bounds__(256) void k_gemm_n64(
    const unsigned short* __restrict__ A, const unsigned short* __restrict__ BT,
    const float* __restrict__ bias, const float* __restrict__ res,
    float* __restrict__ outf, int K, int N) {
  __shared__ unsigned short As[128 * 40];
  __shared__ unsigned short Bs[64 * 40];
  int t = threadIdx.x;
  int m0 = blockIdx.y * 128, n0 = blockIdx.x * 64;
  int w = t >> 6, l = t & 63, lr = l & 15, qd = l >> 4;
  int wm = (w >> 1) * 64, wn = (w & 1) * 32;
  f32x4 acc[4][2];
#pragma unroll
  for (int i = 0; i < 4; ++i)
#pragma unroll
    for (int j = 0; j < 2; ++j)
#pragma unroll
      for (int r = 0; r < 4; ++r) acc[i][j][r] = 0.f;
  for (int k0 = 0; k0 < K; k0 += 32) {
    for (int i = t; i < 512; i += 256) {
      int row = i >> 2, ch = i & 3;
      *(float4*)(As + row * 40 + ch * 8) =
          *(const float4*)(A + (size_t)(m0 + row) * K + k0 + ch * 8);
    }
    {
      int row = t >> 2, ch = t & 3;
      if (row < 64)
        *(float4*)(Bs + row * 40 + ch * 8) =
            *(const float4*)(BT + (size_t)(n0 + row) * K + k0 + ch * 8);
    }
    __syncthreads();
    bf16x8 af[4], bfr[2];
#pragma unroll
    for (int mt = 0; mt < 4; ++mt)
      af[mt] = *(const bf16x8*)(As + (wm + mt * 16 + lr) * 40 + qd * 8);
#pragma unroll
    for (int nt = 0; nt < 2; ++nt)
      bfr[nt] = *(const bf16x8*)(Bs + (wn + nt * 16 + lr) * 40 + qd * 8);
#pragma unroll
    for (int mt = 0; mt < 4; ++mt)
#pragma unroll
      for (int nt = 0; nt < 2; ++nt)
        acc[mt][nt] = __builtin_amdgcn_mfma_f32_16x16x32_bf16(af[mt], bfr[nt],
                                                              acc[mt][nt], 0, 0, 0);
    __syncthreads();
  }
#pragma unroll
  for (int mt = 0; mt < 4; ++mt) {
#pragma unroll
    for (int nt = 0; nt < 2; ++nt) {
#pragma unroll
      for (int r = 0; r < 4; ++r) {
        size_t m = (size_t)m0 + wm + mt * 16 + qd * 4 + r;
        int c = n0 + wn + nt * 16 + lr;
        float val = acc[mt][nt][r] + bias[c] + res[m * N + c];
        outf[m * N + c] = val;
      }
    }
  }
}

// ---------------- flash attention v2: S^T MFMA, fixed-max softmax ----------------
// grid=(36,8,4), 256 thr; wave w owns q rows [qt*64+w*16, +16).
// Qb: [B*N][256] bf16, pre-scaled by 1/sqrt(32). KVc: [b][1984][512] bf16
// (K at col 0..255, V at 256..511; head h at +h*32). Pads (keys>=1959) zeroed.
__global__ __launch_bounds__(256) void k_attn2(
    const unsigned short* __restrict__ Qb, const unsigned short* __restrict__ KVc,
    unsigned short* __restrict__ outb) {
  int qt = blockIdx.x, h = blockIdx.y, b = blockIdx.z;
  int t = threadIdx.x, w = t >> 6, l = t & 63, lr = l & 15, qd = l >> 4;
  __shared__ __align__(16) unsigned short Vt[32][72];     // [d][key]
  __shared__ __align__(16) unsigned short Pq[4][16][72];  // [wave][q][key]
  __shared__ float ls[4][16];
  int q0 = qt * 64 + w * 16;
  // Q as B-operand: B[k=d=qd*8+j][n=q=lr]
  bf16x8 qf = *(const bf16x8*)(Qb + ((size_t)(b * NTOK) + q0 + lr) * 256 + h * 32 + qd * 8);
  const unsigned short* kvb = KVc + (size_t)b * NKC * 512;
  f32x4 oa[2];
  float l_run = 0.f;
#pragma unroll
  for (int r = 0; r < 4; ++r) { oa[0][r] = 0.f; oa[1][r] = 0.f; }
  for (int kt = 0; kt < KT; ++kt) {
    int kb = kt * 64;
    __syncthreads();  // previous tile's Vt fully consumed
    {  // stage V transposed: wave w -> d rows [w*8, w*8+8), key = l
      bf16x8 vv = *(const bf16x8*)(kvb + ((size_t)(kb + l)) * 512 + 256 + h * 32 + w * 8);
#pragma unroll
      for (int j = 0; j < 8; ++j) Vt[w * 8 + j][l] = (unsigned short)vv[j];
    }
    __syncthreads();
    // S^T = K Q^T: A = K rows (m=key), B = Q. D[key=qd*4+r (+nt*16)][q=lr]
    f32x4 p4[4];
#pragma unroll
    for (int nt = 0; nt < 4; ++nt) {
      bf16x8 kf = *(const bf16x8*)(kvb + ((size_t)(kb + nt * 16 + lr)) * 512 + h * 32 + qd * 8);
      f32x4 z; z[0] = 0.f; z[1] = 0.f; z[2] = 0.f; z[3] = 0.f;
      p4[nt] = __builtin_amdgcn_mfma_f32_16x16x32_bf16(kf, qf, z, 0, 0, 0);
    }
    // fixed-max softmax numerator: p = exp(s); scores are O(1) by construction
#pragma unroll
    for (int nt = 0; nt < 4; ++nt)
#pragma unroll
      for (int r = 0; r < 4; ++r) p4[nt][r] = __expf(p4[nt][r]);
    if (kt == KT - 1) {  // zero pad keys (compact index >= NKEEP)
#pragma unroll
      for (int nt = 0; nt < 4; ++nt)
#pragma unroll
        for (int r = 0; r < 4; ++r)
          p4[nt][r] = (nt * 16 + qd * 4 + r < KREM) ? p4[nt][r] : 0.f;
    }
    float psum = 0.f;
#pragma unroll
    for (int nt = 0; nt < 4; ++nt)
#pragma unroll
      for (int r = 0; r < 4; ++r) psum += p4[nt][r];
    psum += __shfl_xor(psum, 16);
    psum += __shfl_xor(psum, 32);
    l_run += psum;
    // store P^T -> Pq[w][q=lr][key], 4 packed b64 writes
#pragma unroll
    for (int nt = 0; nt < 4; ++nt) {
      union { ushort4 u4; __hip_bfloat162 h2[2]; } pu;
      pu.h2[0] = __float22bfloat162_rn(make_float2(p4[nt][0], p4[nt][1]));
      pu.h2[1] = __float22bfloat162_rn(make_float2(p4[nt][2], p4[nt][3]));
      *(ushort4*)(&Pq[w][lr][nt * 16 + qd * 4]) = pu.u4;
    }
    // O += P V : A[m=q=lr][k=key] from Pq (same wave), B[k=key][n=d] from Vt
#pragma unroll
    for (int kh = 0; kh < 2; ++kh) {
      bf16x8 pf = *(const bf16x8*)(&Pq[w][lr][kh * 32 + qd * 8]);
#pragma unroll
      for (int dh = 0; dh < 2; ++dh) {
        bf16x8 vf = *(const bf16x8*)(&Vt[dh * 16 + lr][kh * 32 + qd * 8]);
        oa[dh] = __builtin_amdgcn_mfma_f32_16x16x32_bf16(pf, vf, oa[dh], 0, 0, 0);
      }
    }
  }
  if (qd == 0) ls[w][lr] = l_run;  // same-wave LDS, in-order
#pragma unroll
  for (int r = 0; r < 4; ++r) {
    float inv = 1.f / ls[w][qd * 4 + r];
    size_t row = (size_t)b * NTOK + q0 + qd * 4 + r;
    outb[row * 256 + h * 32 + lr] = f2bf(oa[0][r] * inv);
    outb[row * 256 + h * 32 + 16 + lr] = f2bf(oa[1][r] * inv);
  }
}

// ---------------- final mean over tokens ----------------
__global__ __launch_bounds__(256) void k_mean_partial(const float* __restrict__ in,
                                                      float* __restrict__ part) {
  int blk = blockIdx.x;
  int b = blk / 36, ch = blk % 36;
  int d = threadIdx.x;
  const float* p = in + (size_t)(b * NTOK + ch * 64) * DIM + d;
  float s = 0.f;
  for (int n = 0; n < 64; ++n) s += p[(size_t)n * DIM];
  part[(size_t)blk * DIM + d] = s;
}

__global__ __launch_bounds__(256) void k_mean_final(const float* __restrict__ part,
                                                    float* __restrict__ out) {
  int b = blockIdx.x, d = threadIdx.x;
  float s = 0.f;
  for (int c = 0; c < 36; ++c) s += part[(size_t)(b * 36 + c) * DIM + d];
  out[b * DIM + d] = s * (1.0f / NTOK);
}

// ---------------- driver ----------------
extern "C" void kernel_launch(void* const* d_in, const int* in_sizes, int n_in,
                              void* d_out, int out_size, void* d_ws, size_t ws_size,
                              hipStream_t stream) {
  (void)in_sizes; (void)n_in; (void)out_size;
  const float* x       = (const float*)d_in[0];
  const float* patch_w = (const float*)d_in[1];
  const float* patch_b = (const float*)d_in[2];
  const float* pos     = (const float*)d_in[3];
  const float* imp_w1  = (const float*)d_in[4];
  const float* imp_b1  = (const float*)d_in[5];
  const float* imp_w2  = (const float*)d_in[6];
  const float* imp_b2  = (const float*)d_in[7];
  const float* ln1_g   = (const float*)d_in[8];
  const float* ln1_b   = (const float*)d_in[9];
  const float* qkv_w   = (const float*)d_in[10];
  const float* qkv_b   = (const float*)d_in[11];
  const float* proj_w  = (const float*)d_in[12];
  const float* proj_b  = (const float*)d_in[13];
  const float* ln2_g   = (const float*)d_in[14];
  const float* ln2_b   = (const float*)d_in[15];
  const float* mlp_w1  = (const float*)d_in[16];
  const float* mlp_b1  = (const float*)d_in[17];
  const float* mlp_w2  = (const float*)d_in[18];
  const float* mlp_b2  = (const float*)d_in[19];
  const float* out_g   = (const float*)d_in[20];
  const float* out_b   = (const float*)d_in[21];
  float* out = (float*)d_out;

  const int M = BATCH * NTOK;                 // 9216
  const size_t TOK = (size_t)M * DIM;         // 2,359,296

  char* p = (char*)d_ws;
  float* tokens = (float*)p;              p += TOK * 4;
  float* scoresp = (float*)p;             p += (size_t)M * 4;
  int* cmap = (int*)p;                    p += (size_t)M * 4;
  unsigned short* act_bf = (unsigned short*)p;  p += TOK * 2;            // LN out / attn out
  unsigned short* Qb = (unsigned short*)p;      p += TOK * 2;            // scaled Q
  unsigned short* kvc = (unsigned short*)p;     p += (size_t)BATCH * NKC * 512 * 2;
  unsigned short* big_bf = (unsigned short*)p;  p += (size_t)M * 1024 * 2;  // mlp hidden
  unsigned short* wq_t = (unsigned short*)p;    p += (size_t)3 * 768 * 256 * 2;
  unsigned short* wp_t = (unsigned short*)p;    p += (size_t)3 * 256 * 256 * 2;
  unsigned short* w1_t = (unsigned short*)p;    p += (size_t)3 * 1024 * 256 * 2;
  unsigned short* w2_t = (unsigned short*)p;    p += (size_t)3 * 256 * 1024 * 2;
  float* fscr = (float*)big_bf;     // final-LN fp32 scratch (big_bf dead by then)
  float* partials = (float*)act_bf; // mean partials (act_bf dead by then)
  if (ws_size < (size_t)(p - (char*)d_ws)) return;

  k_wtrans<<<dim3(768 / 32, 256 / 32, 3), 256, 0, stream>>>(qkv_w, wq_t, 256, 768);
  k_wtrans<<<dim3(256 / 32, 256 / 32, 3), 256, 0, stream>>>(proj_w, wp_t, 256, 256);
  k_wtrans<<<dim3(1024 / 32, 256 / 32, 3), 256, 0, stream>>>(mlp_w1, w1_t, 256, 1024);
  k_wtrans<<<dim3(256 / 32, 1024 / 32, 3), 256, 0, stream>>>(mlp_w2, w2_t, 1024, 256);

  k_patch_embed<<<dim3(M), 256, 0, stream>>>(x, patch_w, patch_b, pos, tokens);
  k_importance<<<dim3(M / 16), 256, 0, stream>>>(tokens, imp_w1, imp_b1, imp_w2, imp_b2, scoresp);
  k_select<<<dim3(BATCH), 256, 0, stream>>>(scoresp, cmap, kvc);

  for (int l = 0; l < 3; ++l) {
    k_ln_bf<<<dim3(M), 256, 0, stream>>>(tokens, act_bf, ln1_g + l * DIM, ln1_b + l * DIM);
    k_gemm_qkv<<<dim3(6, 72), 256, 0, stream>>>(
        act_bf, wq_t + (size_t)l * 768 * 256, qkv_b + l * 768, cmap, Qb, kvc);
    k_attn2<<<dim3(36, NHEADS, BATCH), 256, 0, stream>>>(Qb, kvc, act_bf);
    k_gemm_n64<<<dim3(4, 72), 256, 0, stream>>>(
        act_bf, wp_t + (size_t)l * 256 * 256, proj_b + l * DIM, tokens, tokens, 256, 256);
    k_ln_bf<<<dim3(M), 256, 0, stream>>>(tokens, act_bf, ln2_g + l * DIM, ln2_b + l * DIM);
    k_gemm_bf16<<<dim3(8, 72), 256, 0, stream>>>(
        act_bf, w1_t + (size_t)l * 1024 * 256, mlp_b1 + l * 1024, big_bf, 256, 1024, 1);
    k_gemm_n64<<<dim3(4, 72), 256, 0, stream>>>(
        big_bf, w2_t + (size_t)l * 256 * 1024, mlp_b2 + l * DIM, tokens, tokens, 1024, 256);
  }
  k_ln_f32<<<dim3(M), 256, 0, stream>>>(tokens, fscr, out_g, out_b);
  k_mean_partial<<<dim3(BATCH * 36), 256, 0, stream>>>(fscr, partials);
  k_mean_final<<<dim3(BATCH), 256, 0, stream>>>(partials, out);
}

// Round 4
// 605.641 us; speedup vs baseline: 7.8809x; 1.2868x over previous
//
#include <hip/hip_runtime.h>
#include <hip/hip_bf16.h>
#include <math.h>

// ---------------- problem constants ----------------
#define BATCH 4
#define NTOK  2304      // (96/2)^2
#define DIM   256
#define NHEADS 8
#define HCDIM 48
#define KSEL  345       // int(0.15 * 2304)
#define NKEEP 1959      // 2304 - 345
#define NKC   1984      // padded to 31*64
#define KT    31        // key tiles of 64
#define KREM  39        // real keys in last tile (1959 - 30*64)
#define LN_EPS 1e-5f

typedef unsigned short u16;
typedef __attribute__((ext_vector_type(8))) short bf16x8;  // 8 bf16 (4 VGPRs)
typedef __attribute__((ext_vector_type(4))) float f32x4;   // MFMA accumulator

__device__ __forceinline__ u16 f2bf(float x) {
  union { float f; unsigned u; } v; v.f = x;
  return (u16)((v.u + 0x7FFFu + ((v.u >> 16) & 1u)) >> 16);  // RNE
}

// async global->LDS, 16B per lane; lds dest = wave-uniform base + lane*16
__device__ __forceinline__ void gload_lds16(const u16* g, u16* l) {
  __builtin_amdgcn_global_load_lds((const __attribute__((address_space(1))) void*)g,
                                   (__attribute__((address_space(3))) void*)l, 16, 0, 0);
}

// ---------------- patch embed + pos (fp32) ----------------
__global__ __launch_bounds__(256) void k_patch_embed(
    const float* __restrict__ x, const float* __restrict__ pw,
    const float* __restrict__ pb, const float* __restrict__ pos,
    float* __restrict__ tokens) {
  int blk = blockIdx.x;
  int b = blk / NTOK, n = blk % NTOK;
  int hc = n / HCDIM, wc = n % HCDIM;
  __shared__ float xs[12];
  int t = threadIdx.x;
  if (t < 12) {
    int c = t >> 2, p = (t >> 1) & 1, q = t & 1;
    xs[t] = x[((b * 3 + c) * 96 + (hc * 2 + p)) * 96 + (wc * 2 + q)];
  }
  __syncthreads();
  float acc = pb[t];
#pragma unroll
  for (int i = 0; i < 12; ++i) acc += xs[i] * pw[t * 12 + i];
  tokens[(size_t)(b * NTOK + n) * DIM + t] = acc + pos[n * DIM + t];
}

// ---------------- importance MLP -> scores (fp32, exact) ----------------
__global__ __launch_bounds__(256) void k_importance(
    const float* __restrict__ tokens, const float* __restrict__ w1,
    const float* __restrict__ b1, const float* __restrict__ w2,
    const float* __restrict__ b2, float* __restrict__ scores) {
  __shared__ float ts[16 * 256];
  __shared__ float hw[16 * 256];
  int base = blockIdx.x * 16;
  int t = threadIdx.x;
  for (int i = t; i < 16 * 256; i += 256) ts[i] = tokens[(size_t)base * 256 + i];
  __syncthreads();
  float acc[16];
#pragma unroll
  for (int r = 0; r < 16; ++r) acc[r] = b1[t];
  for (int i = 0; i < 256; ++i) {
    float w = w1[i * 256 + t];
#pragma unroll
    for (int r = 0; r < 16; ++r) acc[r] += ts[r * 256 + i] * w;
  }
  float w2v = w2[t];
#pragma unroll
  for (int r = 0; r < 16; ++r) hw[r * 256 + t] = fmaxf(acc[r], 0.f) * w2v;
  __syncthreads();
  if (t < 16) {
    float s = b2[0];
    for (int i = 0; i < 256; ++i) s += hw[t * 256 + i];
    scores[base + t] = 1.f / (1.f + expf(-s));
  }
}

// ------- exact bottom-k -> compaction map, + zero KV pad rows -------
__global__ __launch_bounds__(256) void k_select(const float* __restrict__ scores,
                                                int* __restrict__ cmap,
                                                u16* __restrict__ kvc) {
  int b = blockIdx.x, t = threadIdx.x;
  __shared__ unsigned sb[NTOK];
  __shared__ int cnt;
  __shared__ int pfl[256], pfe[256];
  __shared__ int remS;
  for (int i = t; i < NTOK; i += 256) sb[i] = __float_as_uint(scores[b * NTOK + i]);
  __syncthreads();
  unsigned prefix = 0;
  int r = KSEL;
  for (int bit = 31; bit >= 0; --bit) {
    if (t == 0) cnt = 0;
    __syncthreads();
    unsigned bmask = 1u << bit;
    unsigned hmask = (bit == 31) ? 0u : ~((bmask << 1) - 1u);
    int local = 0;
    for (int i = t; i < NTOK; i += 256)
      if ((sb[i] & hmask) == prefix && !(sb[i] & bmask)) local++;
    if (local) atomicAdd(&cnt, local);
    __syncthreads();
    int c0 = cnt;
    if (r > c0) { r -= c0; prefix |= bmask; }
    __syncthreads();
  }
  unsigned v = prefix;  // exact k-th smallest bit pattern
  int cl = 0, ce = 0;
  int j0 = t * 9;
  for (int j = j0; j < j0 + 9; ++j) { cl += (sb[j] < v); ce += (sb[j] == v); }
  pfl[t] = cl; pfe[t] = ce;
  __syncthreads();
  if (t == 0) {
    int pl = 0, pe = 0;
    for (int i = 0; i < 256; ++i) {
      int a = pfl[i], e = pfe[i];
      pfl[i] = pl; pfe[i] = pe;
      pl += a; pe += e;
    }
    remS = KSEL - pl;
  }
  __syncthreads();
  int pl = pfl[t], pe = pfe[t], rem = remS;
  for (int j = j0; j < j0 + 9; ++j) {
    bool less = sb[j] < v, eq = sb[j] == v;
    bool drop = less || (eq && pe < rem);
    int dropped_before = pl + (pe < rem ? pe : rem);
    cmap[b * NTOK + j] = drop ? -1 : (j - dropped_before);
    pl += less; pe += eq;
  }
  for (int i = t; i < (NKC - NKEEP) * 512; i += 256)
    kvc[((size_t)b * NKC + NKEEP) * 512 + i] = 0;
}

// ---------------- fast LayerNorm -> bf16: wave per row, 4 rows/block ----------------
__global__ __launch_bounds__(256) void k_ln4bf(
    const float* __restrict__ in, u16* __restrict__ out,
    const float* __restrict__ g, const float* __restrict__ bta) {
  int w = threadIdx.x >> 6, l = threadIdx.x & 63;
  size_t row = (size_t)blockIdx.x * 4 + w;
  float4 v = *(const float4*)(in + row * DIM + l * 4);
  float s = v.x + v.y + v.z + v.w;
  float ss = v.x * v.x + v.y * v.y + v.z * v.z + v.w * v.w;
#pragma unroll
  for (int o = 1; o < 64; o <<= 1) { s += __shfl_xor(s, o); ss += __shfl_xor(ss, o); }
  float m = s * (1.f / DIM);
  float inv = rsqrtf(ss * (1.f / DIM) - m * m + LN_EPS);
  float4 gv = *(const float4*)(g + l * 4);
  float4 bv = *(const float4*)(bta + l * 4);
  union { ushort4 u4; __hip_bfloat162 h2[2]; } o4;
  o4.h2[0] = __float22bfloat162_rn(make_float2((v.x - m) * inv * gv.x + bv.x,
                                               (v.y - m) * inv * gv.y + bv.y));
  o4.h2[1] = __float22bfloat162_rn(make_float2((v.z - m) * inv * gv.z + bv.z,
                                               (v.w - m) * inv * gv.w + bv.w));
  *(ushort4*)(out + row * DIM + l * 4) = o4.u4;
}

// ---------------- fused final LayerNorm + partial token-mean ----------------
// grid (36 chunks, 4 batch); wave w handles 16 rows serially; lane owns 4 d.
__global__ __launch_bounds__(256) void k_lnmean(
    const float* __restrict__ in, const float* __restrict__ g,
    const float* __restrict__ bta, float* __restrict__ part) {
  int chunk = blockIdx.x, b = blockIdx.y;
  int w = threadIdx.x >> 6, l = threadIdx.x & 63;
  float4 gv = *(const float4*)(g + l * 4);
  float4 bv = *(const float4*)(bta + l * 4);
  float4 acc = make_float4(0.f, 0.f, 0.f, 0.f);
  for (int i = 0; i < 16; ++i) {
    size_t row = (size_t)b * NTOK + chunk * 64 + w * 16 + i;
    float4 v = *(const float4*)(in + row * DIM + l * 4);
    float s = v.x + v.y + v.z + v.w;
    float ss = v.x * v.x + v.y * v.y + v.z * v.z + v.w * v.w;
#pragma unroll
    for (int o = 1; o < 64; o <<= 1) { s += __shfl_xor(s, o); ss += __shfl_xor(ss, o); }
    float m = s * (1.f / DIM);
    float inv = rsqrtf(ss * (1.f / DIM) - m * m + LN_EPS);
    acc.x += (v.x - m) * inv * gv.x + bv.x;
    acc.y += (v.y - m) * inv * gv.y + bv.y;
    acc.z += (v.z - m) * inv * gv.z + bv.z;
    acc.w += (v.w - m) * inv * gv.w + bv.w;
  }
  __shared__ float4 red[4][64];
  red[w][l] = acc;
  __syncthreads();
  if (w == 0) {
    float4 a0 = red[0][l], a1 = red[1][l], a2 = red[2][l], a3 = red[3][l];
    float4 tot = make_float4(a0.x + a1.x + a2.x + a3.x, a0.y + a1.y + a2.y + a3.y,
                             a0.z + a1.z + a2.z + a3.z, a0.w + a1.w + a2.w + a3.w);
    *(float4*)(part + ((size_t)b * 36 + chunk) * DIM + l * 4) = tot;
  }
}

__global__ __launch_bounds__(256) void k_mean_final(const float* __restrict__ part,
                                                    float* __restrict__ out) {
  int b = blockIdx.x, d = threadIdx.x;
  float s = 0.f;
  for (int c = 0; c < 36; ++c) s += part[(size_t)(b * 36 + c) * DIM + d];
  out[b * DIM + d] = s * (1.0f / NTOK);
}

// ---------------- weight convert + transpose: W[K][N] f32 -> WT[N][K] bf16 ----------------
__global__ __launch_bounds__(256) void k_wtrans(const float* __restrict__ W,
                                               u16* __restrict__ WT, int K, int N) {
  __shared__ float tile[32][33];
  int nb = blockIdx.x * 32, kb = blockIdx.y * 32;
  const float* Wl = W + (size_t)blockIdx.z * K * N;
  u16* WTl = WT + (size_t)blockIdx.z * K * N;
  int tx = threadIdx.x & 31, ty = threadIdx.x >> 5;
  for (int i = 0; i < 32; i += 8) tile[ty + i][tx] = Wl[(size_t)(kb + ty + i) * N + nb + tx];
  __syncthreads();
  for (int i = 0; i < 32; i += 8)
    WTl[(size_t)(nb + ty + i) * K + kb + tx] = f2bf(tile[tx][ty + i]);
}

// ---------------- bf16 MFMA GEMM 128x128 (async staging): outb = act(A @ BT^T + b) ----------------
__global__ __launch_bounds__(256) void k_gemm_bf16(
    const u16* __restrict__ A, const u16* __restrict__ BT,
    const float* __restrict__ bias, u16* __restrict__ outb,
    int K, int N, int act) {
  __shared__ __align__(16) u16 As[128 * 32];
  __shared__ __align__(16) u16 Bs[128 * 32];
  int t = threadIdx.x;
  int m0 = blockIdx.y * 128, n0 = blockIdx.x * 128;
  int w = t >> 6, l = t & 63, lr = l & 15, qd = l >> 4;
  int wm = (w >> 1) * 64, wn = (w & 1) * 64;
  const u16* gA = A + (size_t)(m0 + w * 16 + (l >> 2)) * K + (l & 3) * 8;
  const u16* gA2 = gA + (size_t)64 * K;
  const u16* gB = BT + (size_t)(n0 + w * 16 + (l >> 2)) * K + (l & 3) * 8;
  const u16* gB2 = gB + (size_t)64 * K;
  f32x4 acc[4][4];
#pragma unroll
  for (int i = 0; i < 4; ++i)
#pragma unroll
    for (int j = 0; j < 4; ++j)
#pragma unroll
      for (int r = 0; r < 4; ++r) acc[i][j][r] = 0.f;
  for (int k0 = 0; k0 < K; k0 += 32) {
    gload_lds16(gA + k0, As + w * 512);
    gload_lds16(gA2 + k0, As + 2048 + w * 512);
    gload_lds16(gB + k0, Bs + w * 512);
    gload_lds16(gB2 + k0, Bs + 2048 + w * 512);
    __syncthreads();
    bf16x8 af[4], bfr[4];
#pragma unroll
    for (int mt = 0; mt < 4; ++mt)
      af[mt] = *(const bf16x8*)(As + (wm + mt * 16 + lr) * 32 + qd * 8);
#pragma unroll
    for (int nt = 0; nt < 4; ++nt)
      bfr[nt] = *(const bf16x8*)(Bs + (wn + nt * 16 + lr) * 32 + qd * 8);
#pragma unroll
    for (int mt = 0; mt < 4; ++mt)
#pragma unroll
      for (int nt = 0; nt < 4; ++nt)
        acc[mt][nt] = __builtin_amdgcn_mfma_f32_16x16x32_bf16(af[mt], bfr[nt],
                                                              acc[mt][nt], 0, 0, 0);
    __syncthreads();
  }
#pragma unroll
  for (int mt = 0; mt < 4; ++mt) {
#pragma unroll
    for (int nt = 0; nt < 4; ++nt) {
#pragma unroll
      for (int r = 0; r < 4; ++r) {
        size_t m = (size_t)m0 + wm + mt * 16 + qd * 4 + r;
        int c = n0 + wn + nt * 16 + lr;
        float val = acc[mt][nt][r] + bias[c];
        if (act) val = 0.5f * val * (1.f + erff(val * 0.70710678118654752f));
        outb[m * N + c] = f2bf(val);
      }
    }
  }
}

// ------------ QKV GEMM 128x128 (async staging): Q scaled, KV compacted -------------
__global__ __launch_bounds__(256) void k_gemm_qkv(
    const u16* __restrict__ A, const u16* __restrict__ BT,
    const float* __restrict__ bias, const int* __restrict__ cmap,
    u16* __restrict__ Qb, u16* __restrict__ KVc) {
  const int K = 256, N = 768;
  __shared__ __align__(16) u16 As[128 * 32];
  __shared__ __align__(16) u16 Bs[128 * 32];
  int t = threadIdx.x;
  int m0 = blockIdx.y * 128, n0 = blockIdx.x * 128;
  int w = t >> 6, l = t & 63, lr = l & 15, qd = l >> 4;
  int wm = (w >> 1) * 64, wn = (w & 1) * 64;
  const u16* gA = A + (size_t)(m0 + w * 16 + (l >> 2)) * K + (l & 3) * 8;
  const u16* gA2 = gA + (size_t)64 * K;
  const u16* gB = BT + (size_t)(n0 + w * 16 + (l >> 2)) * K + (l & 3) * 8;
  const u16* gB2 = gB + (size_t)64 * K;
  f32x4 acc[4][4];
#pragma unroll
  for (int i = 0; i < 4; ++i)
#pragma unroll
    for (int j = 0; j < 4; ++j)
#pragma unroll
      for (int r = 0; r < 4; ++r) acc[i][j][r] = 0.f;
  for (int k0 = 0; k0 < K; k0 += 32) {
    gload_lds16(gA + k0, As + w * 512);
    gload_lds16(gA2 + k0, As + 2048 + w * 512);
    gload_lds16(gB + k0, Bs + w * 512);
    gload_lds16(gB2 + k0, Bs + 2048 + w * 512);
    __syncthreads();
    bf16x8 af[4], bfr[4];
#pragma unroll
    for (int mt = 0; mt < 4; ++mt)
      af[mt] = *(const bf16x8*)(As + (wm + mt * 16 + lr) * 32 + qd * 8);
#pragma unroll
    for (int nt = 0; nt < 4; ++nt)
      bfr[nt] = *(const bf16x8*)(Bs + (wn + nt * 16 + lr) * 32 + qd * 8);
#pragma unroll
    for (int mt = 0; mt < 4; ++mt)
#pragma unroll
      for (int nt = 0; nt < 4; ++nt)
        acc[mt][nt] = __builtin_amdgcn_mfma_f32_16x16x32_bf16(af[mt], bfr[nt],
                                                              acc[mt][nt], 0, 0, 0);
    __syncthreads();
  }
  bool isQ = (n0 + wn) < 256;  // wave-uniform
#pragma unroll
  for (int mt = 0; mt < 4; ++mt) {
#pragma unroll
    for (int r = 0; r < 4; ++r) {
      int m = m0 + wm + mt * 16 + qd * 4 + r;
      int cpos = isQ ? 0 : cmap[m];
      int b = m / NTOK;
#pragma unroll
      for (int nt = 0; nt < 4; ++nt) {
        int c = n0 + wn + nt * 16 + lr;
        float val = acc[mt][nt][r] + bias[c];
        if (isQ) {
          Qb[(size_t)m * 256 + c] = f2bf(val * 0.17677669529663687f);
        } else if (cpos >= 0) {
          KVc[((size_t)b * NKC + cpos) * 512 + (c - 256)] = f2bf(val);
        }
      }
    }
  }
}

// ------------- bf16 MFMA GEMM 128x64 (async staging): outf = res + A @ BT^T + b -------------
__global__ __launch_bounds__(256) void k_gemm_n64(
    const u16* __restrict__ A, const u16* __restrict__ BT,
    const float* __restrict__ bias, const float* __restrict__ res,
    float* __restrict__ outf, int K, int N) {
  __shared__ __align__(16) u16 As[128 * 32];
  __shared__ __align__(16) u16 Bs[64 * 32];
  int t = threadIdx.x;
  int m0 = blockIdx.y * 128, n0 = blockIdx.x * 64;
  int w = t >> 6, l = t & 63, lr = l & 15, qd = l >> 4;
  int wm = (w >> 1) * 64, wn = (w & 1) * 32;
  const u16* gA = A + (size_t)(m0 + w * 16 + (l >> 2)) * K + (l & 3) * 8;
  const u16* gA2 = gA + (size_t)64 * K;
  const u16* gB = BT + (size_t)(n0 + w * 16 + (l >> 2)) * K + (l & 3) * 8;
  f32x4 acc[4][2];
#pragma unroll
  for (int i = 0; i < 4; ++i)
#pragma unroll
    for (int j = 0; j < 2; ++j)
#pragma unroll
      for (int r = 0; r < 4; ++r) acc[i][j][r] = 0.f;
  for (int k0 = 0; k0 < K; k0 += 32) {
    gload_lds16(gA + k0, As + w * 512);
    gload_lds16(gA2 + k0, As + 2048 + w * 512);
    gload_lds16(gB + k0, Bs + w * 512);
    __syncthreads();
    bf16x8 af[4], bfr[2];
#pragma unroll
    for (int mt = 0; mt < 4; ++mt)
      af[mt] = *(const bf16x8*)(As + (wm + mt * 16 + lr) * 32 + qd * 8);
#pragma unroll
    for (int nt = 0; nt < 2; ++nt)
      bfr[nt] = *(const bf16x8*)(Bs + (wn + nt * 16 + lr) * 32 + qd * 8);
#pragma unroll
    for (int mt = 0; mt < 4; ++mt)
#pragma unroll
      for (int nt = 0; nt < 2; ++nt)
        acc[mt][nt] = __builtin_amdgcn_mfma_f32_16x16x32_bf16(af[mt], bfr[nt],
                                                              acc[mt][nt], 0, 0, 0);
    __syncthreads();
  }
#pragma unroll
  for (int mt = 0; mt < 4; ++mt) {
#pragma unroll
    for (int nt = 0; nt < 2; ++nt) {
#pragma unroll
      for (int r = 0; r < 4; ++r) {
        size_t m = (size_t)m0 + wm + mt * 16 + qd * 4 + r;
        int c = n0 + wn + nt * 16 + lr;
        outf[m * N + c] = acc[mt][nt][r] + bias[c] + res[m * N + c];
      }
    }
  }
}

// ---------------- flash attention v3: LDS-staged K (async), double-buffered, 1 barrier/iter ----------------
// grid=(36,8,4), 256 thr; wave w owns q rows [qt*64+w*16, +16).
__global__ __launch_bounds__(256) void k_attn3(
    const u16* __restrict__ Qb, const u16* __restrict__ KVc,
    u16* __restrict__ outb) {
  int qt = blockIdx.x, h = blockIdx.y, b = blockIdx.z;
  int t = threadIdx.x, w = t >> 6, l = t & 63, lr = l & 15, qd = l >> 4;
  __shared__ __align__(16) u16 Ks[2][64 * 32];   // [buf][key][d] row-major
  __shared__ __align__(16) u16 Vt[2][32][72];    // [buf][d][key] padded
  __shared__ __align__(16) u16 Pq[4][16][72];    // per-wave P^T [q][key]
  __shared__ float ls[4][16];
  int q0 = qt * 64 + w * 16;
  bf16x8 qf = *(const bf16x8*)(Qb + ((size_t)(b * NTOK) + q0 + lr) * 256 + h * 32 + qd * 8);
  const u16* kvb = KVc + (size_t)b * NKC * 512;
  // K gptr: thread t covers (key = t>>2, d-chunk = t&3) -> linear LDS order
  const u16* gK = kvb + (size_t)(t >> 2) * 512 + h * 32 + (t & 3) * 8;
  // V gptr: wave w covers d rows [w*8,+8), key = l (conflict-free transposed write)
  const u16* gV = kvb + (size_t)l * 512 + 256 + h * 32 + w * 8;
  // prologue: tile 0 in flight
  gload_lds16(gK, &Ks[0][w * 512]);
  bf16x8 vr = *(const bf16x8*)(gV);
  f32x4 oa[2];
  float l_run = 0.f;
#pragma unroll
  for (int r = 0; r < 4; ++r) { oa[0][r] = 0.f; oa[1][r] = 0.f; }
  for (int kt = 0; kt < KT; ++kt) {
    int buf = kt & 1;
    // commit V tile kt (register -> transposed LDS)
#pragma unroll
    for (int j = 0; j < 8; ++j) Vt[buf][w * 8 + j][l] = (u16)vr[j];
    __syncthreads();  // Ks[buf] (async) + Vt[buf] ready; prev compute done
    if (kt + 1 < KT) {  // prefetch tile kt+1 (overlaps compute below)
      size_t off = (size_t)(kt + 1) * 64 * 512;
      gload_lds16(gK + off, &Ks[buf ^ 1][w * 512]);
      vr = *(const bf16x8*)(gV + off);
    }
    // S^T = K Q^T
    f32x4 p4[4];
#pragma unroll
    for (int nt = 0; nt < 4; ++nt) {
      bf16x8 kf = *(const bf16x8*)(&Ks[buf][(nt * 16 + lr) * 32 + qd * 8]);
      f32x4 z; z[0] = 0.f; z[1] = 0.f; z[2] = 0.f; z[3] = 0.f;
      p4[nt] = __builtin_amdgcn_mfma_f32_16x16x32_bf16(kf, qf, z, 0, 0, 0);
    }
#pragma unroll
    for (int nt = 0; nt < 4; ++nt)
#pragma unroll
      for (int r = 0; r < 4; ++r) p4[nt][r] = __expf(p4[nt][r]);
    if (kt == KT - 1) {  // zero pad keys
#pragma unroll
      for (int nt = 0; nt < 4; ++nt)
#pragma unroll
        for (int r = 0; r < 4; ++r)
          p4[nt][r] = (nt * 16 + qd * 4 + r < KREM) ? p4[nt][r] : 0.f;
    }
    float psum = 0.f;
#pragma unroll
    for (int nt = 0; nt < 4; ++nt)
#pragma unroll
      for (int r = 0; r < 4; ++r) psum += p4[nt][r];
    psum += __shfl_xor(psum, 16);
    psum += __shfl_xor(psum, 32);
    l_run += psum;
#pragma unroll
    for (int nt = 0; nt < 4; ++nt) {
      union { ushort4 u4; __hip_bfloat162 h2[2]; } pu;
      pu.h2[0] = __float22bfloat162_rn(make_float2(p4[nt][0], p4[nt][1]));
      pu.h2[1] = __float22bfloat162_rn(make_float2(p4[nt][2], p4[nt][3]));
      *(ushort4*)(&Pq[w][lr][nt * 16 + qd * 4]) = pu.u4;
    }
#pragma unroll
    for (int kh = 0; kh < 2; ++kh) {
      bf16x8 pf = *(const bf16x8*)(&Pq[w][lr][kh * 32 + qd * 8]);
#pragma unroll
      for (int dh = 0; dh < 2; ++dh) {
        bf16x8 vf = *(const bf16x8*)(&Vt[buf][dh * 16 + lr][kh * 32 + qd * 8]);
        oa[dh] = __builtin_amdgcn_mfma_f32_16x16x32_bf16(pf, vf, oa[dh], 0, 0, 0);
      }
    }
  }
  if (qd == 0) ls[w][lr] = l_run;
#pragma unroll
  for (int r = 0; r < 4; ++r) {
    float inv = 1.f / ls[w][qd * 4 + r];
    size_t row = (size_t)b * NTOK + q0 + qd * 4 + r;
    outb[row * 256 + h * 32 + lr] = f2bf(oa[0][r] * inv);
    outb[row * 256 + h * 32 + 16 + lr] = f2bf(oa[1][r] * inv);
  }
}

// ---------------- driver ----------------
extern "C" void kernel_launch(void* const* d_in, const int* in_sizes, int n_in,
                              void* d_out, int out_size, void* d_ws, size_t ws_size,
                              hipStream_t stream) {
  (void)in_sizes; (void)n_in; (void)out_size;
  const float* x       = (const float*)d_in[0];
  const float* patch_w = (const float*)d_in[1];
  const float* patch_b = (const float*)d_in[2];
  const float* pos     = (const float*)d_in[3];
  const float* imp_w1  = (const float*)d_in[4];
  const float* imp_b1  = (const float*)d_in[5];
  const float* imp_w2  = (const float*)d_in[6];
  const float* imp_b2  = (const float*)d_in[7];
  const float* ln1_g   = (const float*)d_in[8];
  const float* ln1_b   = (const float*)d_in[9];
  const float* qkv_w   = (const float*)d_in[10];
  const float* qkv_b   = (const float*)d_in[11];
  const float* proj_w  = (const float*)d_in[12];
  const float* proj_b  = (const float*)d_in[13];
  const float* ln2_g   = (const float*)d_in[14];
  const float* ln2_b   = (const float*)d_in[15];
  const float* mlp_w1  = (const float*)d_in[16];
  const float* mlp_b1  = (const float*)d_in[17];
  const float* mlp_w2  = (const float*)d_in[18];
  const float* mlp_b2  = (const float*)d_in[19];
  const float* out_g   = (const float*)d_in[20];
  const float* out_b   = (const float*)d_in[21];
  float* out = (float*)d_out;

  const int M = BATCH * NTOK;                 // 9216
  const size_t TOK = (size_t)M * DIM;         // 2,359,296

  char* p = (char*)d_ws;
  float* tokens = (float*)p;       p += TOK * 4;
  float* scoresp = (float*)p;      p += (size_t)M * 4;
  int* cmap = (int*)p;             p += (size_t)M * 4;
  u16* act_bf = (u16*)p;           p += TOK * 2;
  u16* Qb = (u16*)p;               p += TOK * 2;
  u16* kvc = (u16*)p;              p += (size_t)BATCH * NKC * 512 * 2;
  u16* big_bf = (u16*)p;           p += (size_t)M * 1024 * 2;
  u16* wq_t = (u16*)p;             p += (size_t)3 * 768 * 256 * 2;
  u16* wp_t = (u16*)p;             p += (size_t)3 * 256 * 256 * 2;
  u16* w1_t = (u16*)p;             p += (size_t)3 * 1024 * 256 * 2;
  u16* w2_t = (u16*)p;             p += (size_t)3 * 256 * 1024 * 2;
  float* partials = (float*)act_bf;  // mean partials (act_bf dead by then)
  if (ws_size < (size_t)(p - (char*)d_ws)) return;

  k_wtrans<<<dim3(768 / 32, 256 / 32, 3), 256, 0, stream>>>(qkv_w, wq_t, 256, 768);
  k_wtrans<<<dim3(256 / 32, 256 / 32, 3), 256, 0, stream>>>(proj_w, wp_t, 256, 256);
  k_wtrans<<<dim3(1024 / 32, 256 / 32, 3), 256, 0, stream>>>(mlp_w1, w1_t, 256, 1024);
  k_wtrans<<<dim3(256 / 32, 1024 / 32, 3), 256, 0, stream>>>(mlp_w2, w2_t, 1024, 256);

  k_patch_embed<<<dim3(M), 256, 0, stream>>>(x, patch_w, patch_b, pos, tokens);
  k_importance<<<dim3(M / 16), 256, 0, stream>>>(tokens, imp_w1, imp_b1, imp_w2, imp_b2, scoresp);
  k_select<<<dim3(BATCH), 256, 0, stream>>>(scoresp, cmap, kvc);

  for (int l = 0; l < 3; ++l) {
    k_ln4bf<<<dim3(M / 4), 256, 0, stream>>>(tokens, act_bf, ln1_g + l * DIM, ln1_b + l * DIM);
    k_gemm_qkv<<<dim3(6, 72), 256, 0, stream>>>(
        act_bf, wq_t + (size_t)l * 768 * 256, qkv_b + l * 768, cmap, Qb, kvc);
    k_attn3<<<dim3(36, NHEADS, BATCH), 256, 0, stream>>>(Qb, kvc, act_bf);
    k_gemm_n64<<<dim3(4, 72), 256, 0, stream>>>(
        act_bf, wp_t + (size_t)l * 256 * 256, proj_b + l * DIM, tokens, tokens, 256, 256);
    k_ln4bf<<<dim3(M / 4), 256, 0, stream>>>(tokens, act_bf, ln2_g + l * DIM, ln2_b + l * DIM);
    k_gemm_bf16<<<dim3(8, 72), 256, 0, stream>>>(
        act_bf, w1_t + (size_t)l * 1024 * 256, mlp_b1 + l * 1024, big_bf, 256, 1024, 1);
    k_gemm_n64<<<dim3(4, 72), 256, 0, stream>>>(
        big_bf, w2_t + (size_t)l * 256 * 1024, mlp_b2 + l * DIM, tokens, tokens, 1024, 256);
  }
  k_lnmean<<<dim3(36, BATCH), 256, 0, stream>>>(tokens, out_g, out_b, partials);
  k_mean_final<<<dim3(BATCH), 256, 0, stream>>>(partials, out);
}